// Round 11
// baseline (104.798 us; speedup 1.0000x reference)
//
#include <hip/hip_runtime.h>
#include <hip/hip_fp16.h>
#include <math.h>

#define BATCH 131072
#define NSTEPS 256
#define LGN 10
#define NPTS 1024          // (1 << LGN)
#define ZSPAN 16.0f        // z in [-8, 8]
#define ZSCALE 64.0f       // NPTS / ZSPAN
#define DZ 0.015625f       // ZSPAN / NPTS
#define MU_C 0.72134752044448170367f   // (mu - sigma^2/2)/ln2 = 0.5/ln2
#define SD_C 1.4426950408889634f       // sigma/ln2

using f32x2 = __attribute__((ext_vector_type(2))) float;

__device__ __forceinline__ float fast_exp(float x) {
    return __builtin_amdgcn_exp2f(x * 1.44269504088896340736f);
}
__device__ __forceinline__ float fast_rcp(float x) {
    return __builtin_amdgcn_rcpf(x);
}
__device__ __forceinline__ float sigmoidf_fast(float x) {
    return fast_rcp(1.0f + fast_exp(-x));
}

#define REP32(M) M(0) M(1) M(2) M(3) M(4) M(5) M(6) M(7) \
                 M(8) M(9) M(10) M(11) M(12) M(13) M(14) M(15) \
                 M(16) M(17) M(18) M(19) M(20) M(21) M(22) M(23) \
                 M(24) M(25) M(26) M(27) M(28) M(29) M(30) M(31)

#define REP16(M) M(0) M(1) M(2) M(3) M(4) M(5) M(6) M(7) \
                 M(8) M(9) M(10) M(11) M(12) M(13) M(14) M(15)

// Shared MLP+tangent body (see R4). Produces h and pre-sigmoid tangent acc.
#define MLP_BODY(W1r, B1, W2r, B2, W3r, b3v, t, s, sd, H, HACC) \
    { \
        const float __t = (t), __s = (s), __sd = (sd); \
        f32x2 acc2 = {(b3v), 0.0f}; \
        REP32(MLP_L1) \
        REP32(MLP_ROW) \
        H = sigmoidf_fast(acc2.x); \
        HACC = acc2.y; \
    }

#define MLP_L1(j) f32x2 at##j; { \
    const float2 wv = W1r[j]; \
    const float z  = fmaf(wv.x, __t, fmaf(wv.y, __s, B1[j])); \
    const float zd = wv.y * __sd; \
    const float sg = sigmoidf_fast(z); \
    const float da = sg * (1.0f + z * (1.0f - sg)); \
    at##j = (f32x2){z * sg, da * zd}; }

#define MLP_ROW(j) { \
    const float4 q0 = W2r[(j) * 8 + 0]; \
    const float4 q1 = W2r[(j) * 8 + 1]; \
    const float4 q2 = W2r[(j) * 8 + 2]; \
    const float4 q3 = W2r[(j) * 8 + 3]; \
    const float4 q4 = W2r[(j) * 8 + 4]; \
    const float4 q5 = W2r[(j) * 8 + 5]; \
    const float4 q6 = W2r[(j) * 8 + 6]; \
    const float4 q7 = W2r[(j) * 8 + 7]; \
    f32x2 zza = {B2[j], 0.0f}; \
    f32x2 zzb = {0.0f, 0.0f}; \
    zza += (f32x2){q0.x, q0.x} * at0;  zzb += (f32x2){q0.y, q0.y} * at1; \
    zza += (f32x2){q0.z, q0.z} * at2;  zzb += (f32x2){q0.w, q0.w} * at3; \
    zza += (f32x2){q1.x, q1.x} * at4;  zzb += (f32x2){q1.y, q1.y} * at5; \
    zza += (f32x2){q1.z, q1.z} * at6;  zzb += (f32x2){q1.w, q1.w} * at7; \
    zza += (f32x2){q2.x, q2.x} * at8;  zzb += (f32x2){q2.y, q2.y} * at9; \
    zza += (f32x2){q2.z, q2.z} * at10; zzb += (f32x2){q2.w, q2.w} * at11; \
    zza += (f32x2){q3.x, q3.x} * at12; zzb += (f32x2){q3.y, q3.y} * at13; \
    zza += (f32x2){q3.z, q3.z} * at14; zzb += (f32x2){q3.w, q3.w} * at15; \
    zza += (f32x2){q4.x, q4.x} * at16; zzb += (f32x2){q4.y, q4.y} * at17; \
    zza += (f32x2){q4.z, q4.z} * at18; zzb += (f32x2){q4.w, q4.w} * at19; \
    zza += (f32x2){q5.x, q5.x} * at20; zzb += (f32x2){q5.y, q5.y} * at21; \
    zza += (f32x2){q5.z, q5.z} * at22; zzb += (f32x2){q5.w, q5.w} * at23; \
    zza += (f32x2){q6.x, q6.x} * at24; zzb += (f32x2){q6.y, q6.y} * at25; \
    zza += (f32x2){q6.z, q6.z} * at26; zzb += (f32x2){q6.w, q6.w} * at27; \
    zza += (f32x2){q7.x, q7.x} * at28; zzb += (f32x2){q7.y, q7.y} * at29; \
    zza += (f32x2){q7.z, q7.z} * at30; zzb += (f32x2){q7.w, q7.w} * at31; \
    const f32x2 zzt = zza + zzb; \
    const float zv  = zzt.x; \
    const float sg  = sigmoidf_fast(zv); \
    const float da  = sg * (1.0f + zv * (1.0f - sg)); \
    const float w3  = W3r[j]; \
    acc2 += (f32x2){w3, w3} * (f32x2){zv * sg, da * zzt.y}; \
}

// ---------------------------------------------------------------------------
// Kernel 1a: evaluate packed half2{h, q} at standardized grid points.
// Row st uses s = 2^(mu + (k*DZ - 8)*sd), mu = MU_C*t, sd = SD_C*sqrt(t)+eps.
// ---------------------------------------------------------------------------
__global__ __launch_bounds__(256) void table_eval_kernel(
    const float* __restrict__ ts,
    const float* __restrict__ W1, const float* __restrict__ b1,
    const float* __restrict__ W2, const float* __restrict__ b2,
    const float* __restrict__ W3, const float* __restrict__ b3,
    unsigned int* __restrict__ A)
{
    __shared__ __align__(16) float sW1[64];
    __shared__ float sb1[32];
    __shared__ __align__(16) float sW2[1024];
    __shared__ float sb2[32];
    __shared__ float sW3[32];
    __shared__ float sb3[1];

    const int tid = threadIdx.x;
    for (int i = tid; i < 1024; i += 256) sW2[i] = W2[i];
    if (tid < 64) sW1[tid] = W1[tid];
    if (tid < 32) { sb1[tid] = b1[tid]; sb2[tid] = b2[tid]; sW3[tid] = W3[tid]; }
    if (tid == 0) sb3[0] = b3[0];
    __syncthreads();

    const float2* W1r = (const float2*)sW1;
    const float*  B1  = sb1;
    const float4* W2r = (const float4*)sW2;
    const float*  B2  = sb2;
    const float*  W3r = sW3;
    const float   b3v = sb3[0];

    const int gid = blockIdx.x * 256 + tid;
    const int st = gid >> LGN;
    const int k  = gid & (NPTS - 1);

    const float t  = ts[st];
    const float mu = MU_C * t;
    const float sd = SD_C * __builtin_sqrtf(t) + 1e-4f;
    const float zz = fmaf((float)k, DZ, -8.0f);
    const float s  = __builtin_amdgcn_exp2f(fmaf(zz, sd, mu));

    float h, hacc;
    MLP_BODY(W1r, B1, W2r, B2, W3r, b3v, t, s, 1.0f, h, hacc)

    const float q = h * (1.0f - h) * hacc * s;   // s * dh/ds
    __half2 p = __floats2half2_rn(h, q);
    A[gid] = *(unsigned int*)&p;
}

// ---------------------------------------------------------------------------
// Kernel 1b: pure-memory pair pack: T2[st][k] = {A[st][k], A[st][k+1]}.
// ---------------------------------------------------------------------------
__global__ __launch_bounds__(256) void pack_kernel(
    const unsigned int* __restrict__ A, uint2* __restrict__ T2)
{
    const int gid = blockIdx.x * 256 + threadIdx.x;
    const int k = gid & (NPTS - 1);
    const unsigned int a = A[gid];
    const unsigned int b = A[gid + (k < NPTS - 1 ? 1 : 0)];
    T2[gid] = make_uint2(a, b);
}

// ---------------------------------------------------------------------------
// Kernel 2: SDE path integration.  16-step chunks; sched_barrier(0) pins the
// software pipeline so all 16 paired gathers + 16 noise prefetches are in
// flight before any consume (the compiler otherwise re-rolls the pipeline to
// save registers: R10 showed VGPR=60, ~5 loads in flight).
// ---------------------------------------------------------------------------
__global__ __launch_bounds__(256, 2) void path_kernel(
    const float* __restrict__ noise,   // (NSTEPS, BATCH)
    const float* __restrict__ ts,      // (NSTEPS+1)
    const float* __restrict__ wq,      // scalar
    const uint2* __restrict__ T2,      // (NSTEPS, NPTS) paired entries
    float* __restrict__ out)           // (BATCH)
{
    __shared__ float4 sdt4[NSTEPS];    // {dt, sqrt(dt), c', w'}: u = x*w' + c'
    const int tid = threadIdx.x;
    if (tid < NSTEPS) {
        const float t0  = ts[tid];
        const float dtv = ts[tid + 1] - t0;
        const float sdv = SD_C * __builtin_sqrtf(t0) + 1e-4f;
        const float wp  = fast_rcp(sdv) * ZSCALE;
        const float cp  = 8.0f * ZSCALE - MU_C * t0 * wp;
        sdt4[tid] = make_float4(dtv, __builtin_sqrtf(dtv), cp, wp);
    }
    __syncthreads();

    const int gid = blockIdx.x * 256 + tid;
    const float* np_ = noise + gid;
    const float umax = (float)NPTS - 1.001f;

    float s   = 1.0f;
    float pnl = 0.0f;

    // preload chunk 0 noise (16 values)
    #define NLD0(k) float n##k = np_[(size_t)(k) * BATCH];
    REP16(NLD0)
    #undef NLD0

    #pragma unroll 1
    for (int c = 0; c < NSTEPS / 16; ++c) {
        const int base = c * 16;

        // prefetch next chunk's noise (uniform branch, loads issued early)
        const float* nb = np_ + ((size_t)base + 16) * BATCH;
        #define NDCL(k) float m##k;
        REP16(NDCL)
        #undef NDCL
        if (c < NSTEPS / 16 - 1) {
            #define NPF(k) m##k = nb[(size_t)(k) * BATCH];
            REP16(NPF)
            #undef NPF
        } else {
            #define NZR(k) m##k = 0.0f;
            REP16(NZR)
            #undef NZR
        }

        // s-chain (cheap, serial) + issue all 16 paired gathers.
        // A = dt + dW + mil serves both the s update and the pnl regroup:
        // pnl += sv*(h*A + q*mil).
        #define CH(k) \
            const float4 dq##k = sdt4[base + k]; \
            const float dW##k  = n##k * dq##k.y; \
            const float mil##k = 0.5f * fmaf(dW##k, dW##k, -dq##k.x); \
            const float Af##k  = dq##k.x + dW##k + mil##k; \
            const float sv##k  = s; \
            s = fmaf(s, Af##k, s); \
            const float x##k = __builtin_amdgcn_logf(sv##k); \
            const float u##k = fminf(fmaxf(fmaf(x##k, dq##k.w, dq##k.z), 0.0f), umax); \
            const int   i0##k = (int)u##k; \
            const float f##k  = u##k - (float)i0##k; \
            const uint2 E##k = T2[((size_t)(base + k) << LGN) + i0##k];
        REP16(CH)
        #undef CH

        // pin: nothing (especially PN consumes) may be scheduled across --
        // all 16 gathers + 16 noise prefetches must be issued by here.
        __builtin_amdgcn_sched_barrier(0);

        // consume gathers into pnl
        #define PN(k) { \
            const float2 a0 = __half22float2(*(const __half2*)&E##k.x); \
            const float2 a1 = __half22float2(*(const __half2*)&E##k.y); \
            const float h  = fmaf(f##k, a1.x - a0.x, a0.x); \
            const float q  = fmaf(f##k, a1.y - a0.y, a0.y); \
            const float v  = fmaf(q, mil##k, h * Af##k); \
            pnl = fmaf(sv##k, v, pnl); }
        REP16(PN)
        #undef PN

        // rotate prefetched noise into place
        #define NRT(k) n##k = m##k;
        REP16(NRT)
        #undef NRT
    }

    const float z = fmaxf(0.0f, s - 3.0f);
    const float d = z - pnl - wq[0];
    out[gid] = d * d;
}

// ---------------------------------------------------------------------------
// Fallback: direct per-thread MLP evaluation (R4 kernel) if ws too small.
// ---------------------------------------------------------------------------
__global__ __launch_bounds__(256, 3) void deep_hedging_direct(
    const float* __restrict__ noise, const float* __restrict__ ts,
    const float* __restrict__ w,
    const float* __restrict__ W1, const float* __restrict__ b1,
    const float* __restrict__ W2, const float* __restrict__ b2,
    const float* __restrict__ W3, const float* __restrict__ b3,
    float* __restrict__ out)
{
    __shared__ __align__(16) float sW1[64];
    __shared__ float sb1[32];
    __shared__ __align__(16) float sW2[1024];
    __shared__ float sb2[32];
    __shared__ float sW3[32];
    __shared__ float sb3w[2];
    __shared__ float sts[NSTEPS + 1];

    const int tid = threadIdx.x;
    for (int i = tid; i < 1024; i += 256) sW2[i] = W2[i];
    if (tid < 64) sW1[tid] = W1[tid];
    if (tid < 32) { sb1[tid] = b1[tid]; sb2[tid] = b2[tid]; sW3[tid] = W3[tid]; }
    if (tid == 0) { sb3w[0] = b3[0]; sb3w[1] = w[0]; }
    for (int i = tid; i < NSTEPS + 1; i += 256) sts[i] = ts[i];
    __syncthreads();

    const int gid = blockIdx.x * 256 + tid;
    const float* np_ = noise + gid;

    float s   = 1.0f;
    float pnl = 0.0f;
    const float b3v = sb3w[0];
    const float wv_ = sb3w[1];

    #pragma unroll 1
    for (int st = 0; st < NSTEPS; ++st) {
        int zr = 0;
        asm volatile("" : "+v"(zr));   // block LICM of weight loads
        const float2* W1r = (const float2*)sW1 + zr;
        const float*  B1  = sb1 + zr;
        const float4* W2r = (const float4*)sW2 + zr;
        const float*  B2  = sb2 + zr;
        const float*  W3r = sW3 + zr;

        const float t  = sts[st];
        const float dt = sts[st + 1] - t;
        const float dW = np_[(size_t)st * BATCH] * __builtin_sqrtf(dt);
        const float sd = s;

        float h, hacc;
        MLP_BODY(W1r, B1, W2r, B2, W3r, b3v, t, s, sd, h, hacc)
        const float hd = h * (1.0f - h) * hacc;

        const float mil = 0.5f * (dW * dW - dt);
        const float g1  = s * h;
        const float dg1 = fmaf(sd, h, s * hd);
        const float snew = s + s * dt + s * dW + sd * mil;
        pnl = pnl + g1 * dt + g1 * dW + dg1 * mil;
        s = snew;
    }

    const float z = fmaxf(0.0f, s - 3.0f);
    const float d = z - pnl - wv_;
    out[gid] = d * d;
}

extern "C" void kernel_launch(void* const* d_in, const int* in_sizes, int n_in,
                              void* d_out, int out_size, void* d_ws, size_t ws_size,
                              hipStream_t stream) {
    const float* noise = (const float*)d_in[0];
    const float* ts    = (const float*)d_in[1];
    const float* w     = (const float*)d_in[2];
    const float* W1    = (const float*)d_in[3];
    const float* b1    = (const float*)d_in[4];
    const float* W2    = (const float*)d_in[5];
    const float* b2    = (const float*)d_in[6];
    const float* W3    = (const float*)d_in[7];
    const float* b3    = (const float*)d_in[8];
    float* out = (float*)d_out;

    const size_t nA   = (size_t)NSTEPS * NPTS;            // entries
    const size_t need = nA * (sizeof(unsigned int) + sizeof(uint2));  // 3 MB

    if (ws_size >= need) {
        unsigned int* A = (unsigned int*)d_ws;
        uint2* T2 = (uint2*)((char*)d_ws + nA * sizeof(unsigned int));

        dim3 tb(256), tg(nA / 256);
        table_eval_kernel<<<tg, tb, 0, stream>>>(ts, W1, b1, W2, b2, W3, b3, A);
        pack_kernel<<<tg, tb, 0, stream>>>(A, T2);
        dim3 pb(256), pg(BATCH / 256);
        path_kernel<<<pg, pb, 0, stream>>>(noise, ts, w, T2, out);
    } else {
        dim3 grid(BATCH / 256), block(256);
        deep_hedging_direct<<<grid, block, 0, stream>>>(noise, ts, w, W1, b1,
                                                        W2, b2, W3, b3, out);
    }
}

// Round 12
// 77.152 us; speedup vs baseline: 1.3583x; 1.3583x over previous
//
#include <hip/hip_runtime.h>
#include <hip/hip_fp16.h>
#include <math.h>

#define BATCH 131072
#define NSTEPS 256
#define LGN 10
#define NPTS 1024          // (1 << LGN)
#define ZSPAN 16.0f        // z in [-8, 8]
#define ZSCALE 64.0f       // NPTS / ZSPAN
#define DZ 0.015625f       // ZSPAN / NPTS
#define MU_C 0.72134752044448170367f   // (mu - sigma^2/2)/ln2 = 0.5/ln2
#define SD_C 1.4426950408889634f       // sigma/ln2

using f32x2 = __attribute__((ext_vector_type(2))) float;

__device__ __forceinline__ float fast_exp(float x) {
    return __builtin_amdgcn_exp2f(x * 1.44269504088896340736f);
}
__device__ __forceinline__ float fast_rcp(float x) {
    return __builtin_amdgcn_rcpf(x);
}
__device__ __forceinline__ float sigmoidf_fast(float x) {
    return fast_rcp(1.0f + fast_exp(-x));
}

#define REP32(M) M(0) M(1) M(2) M(3) M(4) M(5) M(6) M(7) \
                 M(8) M(9) M(10) M(11) M(12) M(13) M(14) M(15) \
                 M(16) M(17) M(18) M(19) M(20) M(21) M(22) M(23) \
                 M(24) M(25) M(26) M(27) M(28) M(29) M(30) M(31)

#define REP16(M) M(0) M(1) M(2) M(3) M(4) M(5) M(6) M(7) \
                 M(8) M(9) M(10) M(11) M(12) M(13) M(14) M(15)

// Shared MLP+tangent body (see R4). Produces h and pre-sigmoid tangent acc.
#define MLP_BODY(W1r, B1, W2r, B2, W3r, b3v, t, s, sd, H, HACC) \
    { \
        const float __t = (t), __s = (s), __sd = (sd); \
        f32x2 acc2 = {(b3v), 0.0f}; \
        REP32(MLP_L1) \
        REP32(MLP_ROW) \
        H = sigmoidf_fast(acc2.x); \
        HACC = acc2.y; \
    }

#define MLP_L1(j) f32x2 at##j; { \
    const float2 wv = W1r[j]; \
    const float z  = fmaf(wv.x, __t, fmaf(wv.y, __s, B1[j])); \
    const float zd = wv.y * __sd; \
    const float sg = sigmoidf_fast(z); \
    const float da = sg * (1.0f + z * (1.0f - sg)); \
    at##j = (f32x2){z * sg, da * zd}; }

#define MLP_ROW(j) { \
    const float4 q0 = W2r[(j) * 8 + 0]; \
    const float4 q1 = W2r[(j) * 8 + 1]; \
    const float4 q2 = W2r[(j) * 8 + 2]; \
    const float4 q3 = W2r[(j) * 8 + 3]; \
    const float4 q4 = W2r[(j) * 8 + 4]; \
    const float4 q5 = W2r[(j) * 8 + 5]; \
    const float4 q6 = W2r[(j) * 8 + 6]; \
    const float4 q7 = W2r[(j) * 8 + 7]; \
    f32x2 zza = {B2[j], 0.0f}; \
    f32x2 zzb = {0.0f, 0.0f}; \
    zza += (f32x2){q0.x, q0.x} * at0;  zzb += (f32x2){q0.y, q0.y} * at1; \
    zza += (f32x2){q0.z, q0.z} * at2;  zzb += (f32x2){q0.w, q0.w} * at3; \
    zza += (f32x2){q1.x, q1.x} * at4;  zzb += (f32x2){q1.y, q1.y} * at5; \
    zza += (f32x2){q1.z, q1.z} * at6;  zzb += (f32x2){q1.w, q1.w} * at7; \
    zza += (f32x2){q2.x, q2.x} * at8;  zzb += (f32x2){q2.y, q2.y} * at9; \
    zza += (f32x2){q2.z, q2.z} * at10; zzb += (f32x2){q2.w, q2.w} * at11; \
    zza += (f32x2){q3.x, q3.x} * at12; zzb += (f32x2){q3.y, q3.y} * at13; \
    zza += (f32x2){q3.z, q3.z} * at14; zzb += (f32x2){q3.w, q3.w} * at15; \
    zza += (f32x2){q4.x, q4.x} * at16; zzb += (f32x2){q4.y, q4.y} * at17; \
    zza += (f32x2){q4.z, q4.z} * at18; zzb += (f32x2){q4.w, q4.w} * at19; \
    zza += (f32x2){q5.x, q5.x} * at20; zzb += (f32x2){q5.y, q5.y} * at21; \
    zza += (f32x2){q5.z, q5.z} * at22; zzb += (f32x2){q5.w, q5.w} * at23; \
    zza += (f32x2){q6.x, q6.x} * at24; zzb += (f32x2){q6.y, q6.y} * at25; \
    zza += (f32x2){q6.z, q6.z} * at26; zzb += (f32x2){q6.w, q6.w} * at27; \
    zza += (f32x2){q7.x, q7.x} * at28; zzb += (f32x2){q7.y, q7.y} * at29; \
    zza += (f32x2){q7.z, q7.z} * at30; zzb += (f32x2){q7.w, q7.w} * at31; \
    const f32x2 zzt = zza + zzb; \
    const float zv  = zzt.x; \
    const float sg  = sigmoidf_fast(zv); \
    const float da  = sg * (1.0f + zv * (1.0f - sg)); \
    const float w3  = W3r[j]; \
    acc2 += (f32x2){w3, w3} * (f32x2){zv * sg, da * zzt.y}; \
}

// ---------------------------------------------------------------------------
// Kernel 1a: evaluate packed half2{h, q} at standardized grid points.
// ---------------------------------------------------------------------------
__global__ __launch_bounds__(256) void table_eval_kernel(
    const float* __restrict__ ts,
    const float* __restrict__ W1, const float* __restrict__ b1,
    const float* __restrict__ W2, const float* __restrict__ b2,
    const float* __restrict__ W3, const float* __restrict__ b3,
    unsigned int* __restrict__ A)
{
    __shared__ __align__(16) float sW1[64];
    __shared__ float sb1[32];
    __shared__ __align__(16) float sW2[1024];
    __shared__ float sb2[32];
    __shared__ float sW3[32];
    __shared__ float sb3[1];

    const int tid = threadIdx.x;
    for (int i = tid; i < 1024; i += 256) sW2[i] = W2[i];
    if (tid < 64) sW1[tid] = W1[tid];
    if (tid < 32) { sb1[tid] = b1[tid]; sb2[tid] = b2[tid]; sW3[tid] = W3[tid]; }
    if (tid == 0) sb3[0] = b3[0];
    __syncthreads();

    const float2* W1r = (const float2*)sW1;
    const float*  B1  = sb1;
    const float4* W2r = (const float4*)sW2;
    const float*  B2  = sb2;
    const float*  W3r = sW3;
    const float   b3v = sb3[0];

    const int gid = blockIdx.x * 256 + tid;
    const int st = gid >> LGN;
    const int k  = gid & (NPTS - 1);

    const float t  = ts[st];
    const float mu = MU_C * t;
    const float sd = SD_C * __builtin_sqrtf(t) + 1e-4f;
    const float zz = fmaf((float)k, DZ, -8.0f);
    const float s  = __builtin_amdgcn_exp2f(fmaf(zz, sd, mu));

    float h, hacc;
    MLP_BODY(W1r, B1, W2r, B2, W3r, b3v, t, s, 1.0f, h, hacc)

    const float q = h * (1.0f - h) * hacc * s;   // s * dh/ds
    __half2 p = __floats2half2_rn(h, q);
    A[gid] = *(unsigned int*)&p;
}

// ---------------------------------------------------------------------------
// Kernel 1b: pure-memory pair pack: T2[st][k] = {A[st][k], A[st][k+1]}.
// ---------------------------------------------------------------------------
__global__ __launch_bounds__(256) void pack_kernel(
    const unsigned int* __restrict__ A, uint2* __restrict__ T2)
{
    const int gid = blockIdx.x * 256 + threadIdx.x;
    const int k = gid & (NPTS - 1);
    const unsigned int a = A[gid];
    const unsigned int b = A[gid + (k < NPTS - 1 ? 1 : 0)];
    T2[gid] = make_uint2(a, b);
}

// ---------------------------------------------------------------------------
// Kernel 2: SDE path integration.  16-step chunks.  The 16 paired gathers
// are pinned live at one point by an asm use (data dependence -- the compiler
// cannot re-roll the pipeline, unlike sched_barrier alone, R11) followed by
// sched_barrier(0) so consumes can't hoist above the pin (guide rule #18).
// __launch_bounds__(256,1): occupancy is grid-capped at 2 waves/SIMD, so let
// the allocator use up to 256 VGPRs for the in-flight chunk state.
// ---------------------------------------------------------------------------
__global__ __launch_bounds__(256, 1) void path_kernel(
    const float* __restrict__ noise,   // (NSTEPS, BATCH)
    const float* __restrict__ ts,      // (NSTEPS+1)
    const float* __restrict__ wq,      // scalar
    const uint2* __restrict__ T2,      // (NSTEPS, NPTS) paired entries
    float* __restrict__ out)           // (BATCH)
{
    __shared__ float4 sdt4[NSTEPS];    // {dt, sqrt(dt), c', w'}: u = x*w' + c'
    const int tid = threadIdx.x;
    if (tid < NSTEPS) {
        const float t0  = ts[tid];
        const float dtv = ts[tid + 1] - t0;
        const float sdv = SD_C * __builtin_sqrtf(t0) + 1e-4f;
        const float wp  = fast_rcp(sdv) * ZSCALE;
        const float cp  = 8.0f * ZSCALE - MU_C * t0 * wp;
        sdt4[tid] = make_float4(dtv, __builtin_sqrtf(dtv), cp, wp);
    }
    __syncthreads();

    const int gid = blockIdx.x * 256 + tid;
    const float* np_ = noise + gid;
    const float umax = (float)NPTS - 1.001f;

    float s   = 1.0f;
    float pnl = 0.0f;

    // preload chunk 0 noise (16 values)
    #define NLD0(k) float n##k = np_[(size_t)(k) * BATCH];
    REP16(NLD0)
    #undef NLD0

    #pragma unroll 1
    for (int c = 0; c < NSTEPS / 16; ++c) {
        const int base = c * 16;

        // s-chain (cheap, serial) + issue all 16 paired gathers.
        // A = dt + dW + mil serves both the s update and the pnl regroup:
        // pnl += sv*(h*A + q*mil).
        #define CH(k) \
            const float4 dq##k = sdt4[base + k]; \
            const float dW##k  = n##k * dq##k.y; \
            const float mil##k = 0.5f * fmaf(dW##k, dW##k, -dq##k.x); \
            const float Af##k  = dq##k.x + dW##k + mil##k; \
            const float sv##k  = s; \
            s = fmaf(s, Af##k, s); \
            const float x##k = __builtin_amdgcn_logf(sv##k); \
            const float u##k = fminf(fmaxf(fmaf(x##k, dq##k.w, dq##k.z), 0.0f), umax); \
            const int   i0##k = (int)u##k; \
            const float f##k  = u##k - (float)i0##k; \
            uint2 E##k = T2[((size_t)(base + k) << LGN) + i0##k];
        REP16(CH)
        #undef CH

        // PIN: every E has a data dependence to this point -> all 16 gathers
        // must be issued (and drained once) here; nothing can re-roll them.
        asm volatile("" ::
            "v"(E0.x),  "v"(E0.y),  "v"(E1.x),  "v"(E1.y),
            "v"(E2.x),  "v"(E2.y),  "v"(E3.x),  "v"(E3.y),
            "v"(E4.x),  "v"(E4.y),  "v"(E5.x),  "v"(E5.y),
            "v"(E6.x),  "v"(E6.y),  "v"(E7.x),  "v"(E7.y),
            "v"(E8.x),  "v"(E8.y),  "v"(E9.x),  "v"(E9.y),
            "v"(E10.x), "v"(E10.y), "v"(E11.x), "v"(E11.y),
            "v"(E12.x), "v"(E12.y), "v"(E13.x), "v"(E13.y),
            "v"(E14.x), "v"(E14.y), "v"(E15.x), "v"(E15.y));
        __builtin_amdgcn_sched_barrier(0);

        // prefetch next chunk's noise AFTER the pin: issues during PN,
        // lands during next chunk's CH (not drained by the pin's waitcnt).
        const float* nb = np_ + ((size_t)base + 16) * BATCH;
        #define NDCL(k) float m##k;
        REP16(NDCL)
        #undef NDCL
        if (c < NSTEPS / 16 - 1) {
            #define NPF(k) m##k = nb[(size_t)(k) * BATCH];
            REP16(NPF)
            #undef NPF
        } else {
            #define NZR(k) m##k = 0.0f;
            REP16(NZR)
            #undef NZR
        }

        // consume gathers into pnl
        #define PN(k) { \
            const float2 a0 = __half22float2(*(const __half2*)&E##k.x); \
            const float2 a1 = __half22float2(*(const __half2*)&E##k.y); \
            const float h  = fmaf(f##k, a1.x - a0.x, a0.x); \
            const float q  = fmaf(f##k, a1.y - a0.y, a0.y); \
            const float v  = fmaf(q, mil##k, h * Af##k); \
            pnl = fmaf(sv##k, v, pnl); }
        REP16(PN)
        #undef PN

        // rotate prefetched noise into place
        #define NRT(k) n##k = m##k;
        REP16(NRT)
        #undef NRT
    }

    const float z = fmaxf(0.0f, s - 3.0f);
    const float d = z - pnl - wq[0];
    out[gid] = d * d;
}

// ---------------------------------------------------------------------------
// Fallback: direct per-thread MLP evaluation (R4 kernel) if ws too small.
// ---------------------------------------------------------------------------
__global__ __launch_bounds__(256, 3) void deep_hedging_direct(
    const float* __restrict__ noise, const float* __restrict__ ts,
    const float* __restrict__ w,
    const float* __restrict__ W1, const float* __restrict__ b1,
    const float* __restrict__ W2, const float* __restrict__ b2,
    const float* __restrict__ W3, const float* __restrict__ b3,
    float* __restrict__ out)
{
    __shared__ __align__(16) float sW1[64];
    __shared__ float sb1[32];
    __shared__ __align__(16) float sW2[1024];
    __shared__ float sb2[32];
    __shared__ float sW3[32];
    __shared__ float sb3w[2];
    __shared__ float sts[NSTEPS + 1];

    const int tid = threadIdx.x;
    for (int i = tid; i < 1024; i += 256) sW2[i] = W2[i];
    if (tid < 64) sW1[tid] = W1[tid];
    if (tid < 32) { sb1[tid] = b1[tid]; sb2[tid] = b2[tid]; sW3[tid] = W3[tid]; }
    if (tid == 0) { sb3w[0] = b3[0]; sb3w[1] = w[0]; }
    for (int i = tid; i < NSTEPS + 1; i += 256) sts[i] = ts[i];
    __syncthreads();

    const int gid = blockIdx.x * 256 + tid;
    const float* np_ = noise + gid;

    float s   = 1.0f;
    float pnl = 0.0f;
    const float b3v = sb3w[0];
    const float wv_ = sb3w[1];

    #pragma unroll 1
    for (int st = 0; st < NSTEPS; ++st) {
        int zr = 0;
        asm volatile("" : "+v"(zr));   // block LICM of weight loads
        const float2* W1r = (const float2*)sW1 + zr;
        const float*  B1  = sb1 + zr;
        const float4* W2r = (const float4*)sW2 + zr;
        const float*  B2  = sb2 + zr;
        const float*  W3r = sW3 + zr;

        const float t  = sts[st];
        const float dt = sts[st + 1] - t;
        const float dW = np_[(size_t)st * BATCH] * __builtin_sqrtf(dt);
        const float sd = s;

        float h, hacc;
        MLP_BODY(W1r, B1, W2r, B2, W3r, b3v, t, s, sd, h, hacc)
        const float hd = h * (1.0f - h) * hacc;

        const float mil = 0.5f * (dW * dW - dt);
        const float g1  = s * h;
        const float dg1 = fmaf(sd, h, s * hd);
        const float snew = s + s * dt + s * dW + sd * mil;
        pnl = pnl + g1 * dt + g1 * dW + dg1 * mil;
        s = snew;
    }

    const float z = fmaxf(0.0f, s - 3.0f);
    const float d = z - pnl - wv_;
    out[gid] = d * d;
}

extern "C" void kernel_launch(void* const* d_in, const int* in_sizes, int n_in,
                              void* d_out, int out_size, void* d_ws, size_t ws_size,
                              hipStream_t stream) {
    const float* noise = (const float*)d_in[0];
    const float* ts    = (const float*)d_in[1];
    const float* w     = (const float*)d_in[2];
    const float* W1    = (const float*)d_in[3];
    const float* b1    = (const float*)d_in[4];
    const float* W2    = (const float*)d_in[5];
    const float* b2    = (const float*)d_in[6];
    const float* W3    = (const float*)d_in[7];
    const float* b3    = (const float*)d_in[8];
    float* out = (float*)d_out;

    const size_t nA   = (size_t)NSTEPS * NPTS;            // entries
    const size_t need = nA * (sizeof(unsigned int) + sizeof(uint2));  // 3 MB

    if (ws_size >= need) {
        unsigned int* A = (unsigned int*)d_ws;
        uint2* T2 = (uint2*)((char*)d_ws + nA * sizeof(unsigned int));

        dim3 tb(256), tg(nA / 256);
        table_eval_kernel<<<tg, tb, 0, stream>>>(ts, W1, b1, W2, b2, W3, b3, A);
        pack_kernel<<<tg, tb, 0, stream>>>(A, T2);
        dim3 pb(256), pg(BATCH / 256);
        path_kernel<<<pg, pb, 0, stream>>>(noise, ts, w, T2, out);
    } else {
        dim3 grid(BATCH / 256), block(256);
        deep_hedging_direct<<<grid, block, 0, stream>>>(noise, ts, w, W1, b1,
                                                        W2, b2, W3, b3, out);
    }
}

// Round 14
// 76.054 us; speedup vs baseline: 1.3779x; 1.0144x over previous
//
#include <hip/hip_runtime.h>
#include <hip/hip_fp16.h>
#include <math.h>

#define BATCH 131072
#define NSTEPS 256
#define LGN 10
#define NPTS 1024          // (1 << LGN)
#define ZSPAN 16.0f        // z in [-8, 8]
#define ZSCALE 64.0f       // NPTS / ZSPAN
#define DZ 0.015625f       // ZSPAN / NPTS
#define MU_C 0.72134752044448170367f   // (mu - sigma^2/2)/ln2 = 0.5/ln2
#define SD_C 1.4426950408889634f       // sigma/ln2

using f32x2 = __attribute__((ext_vector_type(2))) float;

__device__ __forceinline__ float fast_exp(float x) {
    return __builtin_amdgcn_exp2f(x * 1.44269504088896340736f);
}
__device__ __forceinline__ float fast_rcp(float x) {
    return __builtin_amdgcn_rcpf(x);
}
__device__ __forceinline__ float sigmoidf_fast(float x) {
    return fast_rcp(1.0f + fast_exp(-x));
}

#define REP32(M) M(0) M(1) M(2) M(3) M(4) M(5) M(6) M(7) \
                 M(8) M(9) M(10) M(11) M(12) M(13) M(14) M(15) \
                 M(16) M(17) M(18) M(19) M(20) M(21) M(22) M(23) \
                 M(24) M(25) M(26) M(27) M(28) M(29) M(30) M(31)

#define REP16(M) M(0) M(1) M(2) M(3) M(4) M(5) M(6) M(7) \
                 M(8) M(9) M(10) M(11) M(12) M(13) M(14) M(15)

#define REP16P(M, P) M(0,P) M(1,P) M(2,P) M(3,P) M(4,P) M(5,P) M(6,P) M(7,P) \
                     M(8,P) M(9,P) M(10,P) M(11,P) M(12,P) M(13,P) M(14,P) M(15,P)

// Shared MLP+tangent body (see R4). Produces h and pre-sigmoid tangent acc.
#define MLP_BODY(W1r, B1, W2r, B2, W3r, b3v, t, s, sd, H, HACC) \
    { \
        const float __t = (t), __s = (s), __sd = (sd); \
        f32x2 acc2 = {(b3v), 0.0f}; \
        REP32(MLP_L1) \
        REP32(MLP_ROW) \
        H = sigmoidf_fast(acc2.x); \
        HACC = acc2.y; \
    }

#define MLP_L1(j) f32x2 at##j; { \
    const float2 wv = W1r[j]; \
    const float z  = fmaf(wv.x, __t, fmaf(wv.y, __s, B1[j])); \
    const float zd = wv.y * __sd; \
    const float sg = sigmoidf_fast(z); \
    const float da = sg * (1.0f + z * (1.0f - sg)); \
    at##j = (f32x2){z * sg, da * zd}; }

#define MLP_ROW(j) { \
    const float4 q0 = W2r[(j) * 8 + 0]; \
    const float4 q1 = W2r[(j) * 8 + 1]; \
    const float4 q2 = W2r[(j) * 8 + 2]; \
    const float4 q3 = W2r[(j) * 8 + 3]; \
    const float4 q4 = W2r[(j) * 8 + 4]; \
    const float4 q5 = W2r[(j) * 8 + 5]; \
    const float4 q6 = W2r[(j) * 8 + 6]; \
    const float4 q7 = W2r[(j) * 8 + 7]; \
    f32x2 zza = {B2[j], 0.0f}; \
    f32x2 zzb = {0.0f, 0.0f}; \
    zza += (f32x2){q0.x, q0.x} * at0;  zzb += (f32x2){q0.y, q0.y} * at1; \
    zza += (f32x2){q0.z, q0.z} * at2;  zzb += (f32x2){q0.w, q0.w} * at3; \
    zza += (f32x2){q1.x, q1.x} * at4;  zzb += (f32x2){q1.y, q1.y} * at5; \
    zza += (f32x2){q1.z, q1.z} * at6;  zzb += (f32x2){q1.w, q1.w} * at7; \
    zza += (f32x2){q2.x, q2.x} * at8;  zzb += (f32x2){q2.y, q2.y} * at9; \
    zza += (f32x2){q2.z, q2.z} * at10; zzb += (f32x2){q2.w, q2.w} * at11; \
    zza += (f32x2){q3.x, q3.x} * at12; zzb += (f32x2){q3.y, q3.y} * at13; \
    zza += (f32x2){q3.z, q3.z} * at14; zzb += (f32x2){q3.w, q3.w} * at15; \
    zza += (f32x2){q4.x, q4.x} * at16; zzb += (f32x2){q4.y, q4.y} * at17; \
    zza += (f32x2){q4.z, q4.z} * at18; zzb += (f32x2){q4.w, q4.w} * at19; \
    zza += (f32x2){q5.x, q5.x} * at20; zzb += (f32x2){q5.y, q5.y} * at21; \
    zza += (f32x2){q5.z, q5.z} * at22; zzb += (f32x2){q5.w, q5.w} * at23; \
    zza += (f32x2){q6.x, q6.x} * at24; zzb += (f32x2){q6.y, q6.y} * at25; \
    zza += (f32x2){q6.z, q6.z} * at26; zzb += (f32x2){q6.w, q6.w} * at27; \
    zza += (f32x2){q7.x, q7.x} * at28; zzb += (f32x2){q7.y, q7.y} * at29; \
    zza += (f32x2){q7.z, q7.z} * at30; zzb += (f32x2){q7.w, q7.w} * at31; \
    const f32x2 zzt = zza + zzb; \
    const float zv  = zzt.x; \
    const float sg  = sigmoidf_fast(zv); \
    const float da  = sg * (1.0f + zv * (1.0f - sg)); \
    const float w3  = W3r[j]; \
    acc2 += (f32x2){w3, w3} * (f32x2){zv * sg, da * zzt.y}; \
}

// ---------------------------------------------------------------------------
// Kernel 1a: evaluate packed half2{h, q} at standardized grid points.
// ---------------------------------------------------------------------------
__global__ __launch_bounds__(256) void table_eval_kernel(
    const float* __restrict__ ts,
    const float* __restrict__ W1, const float* __restrict__ b1,
    const float* __restrict__ W2, const float* __restrict__ b2,
    const float* __restrict__ W3, const float* __restrict__ b3,
    unsigned int* __restrict__ A)
{
    __shared__ __align__(16) float sW1[64];
    __shared__ float sb1[32];
    __shared__ __align__(16) float sW2[1024];
    __shared__ float sb2[32];
    __shared__ float sW3[32];
    __shared__ float sb3[1];

    const int tid = threadIdx.x;
    for (int i = tid; i < 1024; i += 256) sW2[i] = W2[i];
    if (tid < 64) sW1[tid] = W1[tid];
    if (tid < 32) { sb1[tid] = b1[tid]; sb2[tid] = b2[tid]; sW3[tid] = W3[tid]; }
    if (tid == 0) sb3[0] = b3[0];
    __syncthreads();

    const float2* W1r = (const float2*)sW1;
    const float*  B1  = sb1;
    const float4* W2r = (const float4*)sW2;
    const float*  B2  = sb2;
    const float*  W3r = sW3;
    const float   b3v = sb3[0];

    const int gid = blockIdx.x * 256 + tid;
    const int st = gid >> LGN;
    const int k  = gid & (NPTS - 1);

    const float t  = ts[st];
    const float mu = MU_C * t;
    const float sd = SD_C * __builtin_sqrtf(t) + 1e-4f;
    const float zz = fmaf((float)k, DZ, -8.0f);
    const float s  = __builtin_amdgcn_exp2f(fmaf(zz, sd, mu));

    float h, hacc;
    MLP_BODY(W1r, B1, W2r, B2, W3r, b3v, t, s, 1.0f, h, hacc)

    const float q = h * (1.0f - h) * hacc * s;   // s * dh/ds
    __half2 p = __floats2half2_rn(h, q);
    A[gid] = *(unsigned int*)&p;
}

// ---------------------------------------------------------------------------
// Kernel 1b: pure-memory pair pack: T2[st][k] = {A[st][k], A[st][k+1]}.
// ---------------------------------------------------------------------------
__global__ __launch_bounds__(256) void pack_kernel(
    const unsigned int* __restrict__ A, uint2* __restrict__ T2)
{
    const int gid = blockIdx.x * 256 + threadIdx.x;
    const int k = gid & (NPTS - 1);
    const unsigned int a = A[gid];
    const unsigned int b = A[gid + (k < NPTS - 1 ? 1 : 0)];
    T2[gid] = make_uint2(a, b);
}

// ---------------------------------------------------------------------------
// Kernel 2: SDE path integration.
//  - 16-step chunks, manually 2-body unrolled (noise register sets A/B).
//  - Noise prefetch depth 2: body c issues chunk c+2 -> >1 full chunk of
//    latency cover (the R10-R12 plateau was exposed noise latency).
//  - Gathers pinned with READ-WRITE asm ("+v"): PN consumes the asm's
//    outputs, so the IR cannot re-roll the pipeline (R12's read-only pin
//    left VGPR=76: each PN was computed before the pin).
// ---------------------------------------------------------------------------
__global__ __launch_bounds__(256, 1) void path_kernel(
    const float* __restrict__ noise,   // (NSTEPS, BATCH)
    const float* __restrict__ ts,      // (NSTEPS+1)
    const float* __restrict__ wq,      // scalar
    const uint2* __restrict__ T2,      // (NSTEPS, NPTS) paired entries
    float* __restrict__ out)           // (BATCH)
{
    __shared__ float4 sdt4[NSTEPS];    // {dt, sqrt(dt), c', w'}: u = x*w' + c'
    const int tid = threadIdx.x;
    if (tid < NSTEPS) {
        const float t0  = ts[tid];
        const float dtv = ts[tid + 1] - t0;
        const float sdv = SD_C * __builtin_sqrtf(t0) + 1e-4f;
        const float wp  = fast_rcp(sdv) * ZSCALE;
        const float cp  = 8.0f * ZSCALE - MU_C * t0 * wp;
        sdt4[tid] = make_float4(dtv, __builtin_sqrtf(dtv), cp, wp);
    }
    __syncthreads();

    const int gid = blockIdx.x * 256 + tid;
    const float* np_ = noise + gid;
    const float umax = (float)NPTS - 1.001f;

    float s   = 1.0f;
    float pnl = 0.0f;

    // preload noise for chunks 0 (set A) and 1 (set B)
    #define NLA(k) float nA##k = np_[(size_t)(k) * BATCH];
    #define NLB(k) float nB##k = np_[(size_t)(16 + k) * BATCH];
    REP16(NLA)
    REP16(NLB)
    #undef NLA
    #undef NLB

    // per-step: s-chain + gather issue
    #define CHK(k, NP) \
        const float4 dq##k = sdt4[base + k]; \
        const float dW##k  = NP##k * dq##k.y; \
        const float mil##k = 0.5f * fmaf(dW##k, dW##k, -dq##k.x); \
        const float Af##k  = dq##k.x + dW##k + mil##k; \
        const float sv##k  = s; \
        s = fmaf(s, Af##k, s); \
        const float x##k = __builtin_amdgcn_logf(sv##k); \
        const float u##k = fminf(fmaxf(fmaf(x##k, dq##k.w, dq##k.z), 0.0f), umax); \
        const int   i0##k = (int)u##k; \
        const float f##k  = u##k - (float)i0##k; \
        unsigned long long E##k = \
            ((const unsigned long long*)(T2 + ((size_t)(base + k) << LGN)))[i0##k];

    // noise prefetch for chunk c+2 (overwrites this body's set, already read)
    #define NPF(k, NP) NP##k = np_[(size_t)(pfb + k) * BATCH];

    // consume: f32 interp into pnl (reads E only through the pin)
    #define PNK(k) { \
        const uint2 eu = __builtin_bit_cast(uint2, E##k); \
        const float2 a0 = __half22float2(*(const __half2*)&eu.x); \
        const float2 a1 = __half22float2(*(const __half2*)&eu.y); \
        const float h  = fmaf(f##k, a1.x - a0.x, a0.x); \
        const float q  = fmaf(f##k, a1.y - a0.y, a0.y); \
        const float v  = fmaf(q, mil##k, h * Af##k); \
        pnl = fmaf(sv##k, v, pnl); }

    #define BODY(cexpr, NP) { \
        const int base = (cexpr) * 16; \
        const int pfb  = min(base + 32, NSTEPS - 16); \
        REP16P(CHK, NP) \
        __builtin_amdgcn_sched_barrier(0); \
        REP16P(NPF, NP) \
        asm volatile("" : "+v"(E0), "+v"(E1), "+v"(E2), "+v"(E3), \
                          "+v"(E4), "+v"(E5), "+v"(E6), "+v"(E7)); \
        asm volatile("" : "+v"(E8),  "+v"(E9),  "+v"(E10), "+v"(E11), \
                          "+v"(E12), "+v"(E13), "+v"(E14), "+v"(E15)); \
        __builtin_amdgcn_sched_barrier(0); \
        REP16(PNK) \
    }

    #pragma unroll 1
    for (int cc = 0; cc < NSTEPS / 32; ++cc) {
        BODY(cc * 2,     nA)
        BODY(cc * 2 + 1, nB)
    }

    #undef BODY
    #undef PNK
    #undef NPF
    #undef CHK

    const float z = fmaxf(0.0f, s - 3.0f);
    const float d = z - pnl - wq[0];
    out[gid] = d * d;
}

// ---------------------------------------------------------------------------
// Fallback: direct per-thread MLP evaluation (R4 kernel) if ws too small.
// ---------------------------------------------------------------------------
__global__ __launch_bounds__(256, 3) void deep_hedging_direct(
    const float* __restrict__ noise, const float* __restrict__ ts,
    const float* __restrict__ w,
    const float* __restrict__ W1, const float* __restrict__ b1,
    const float* __restrict__ W2, const float* __restrict__ b2,
    const float* __restrict__ W3, const float* __restrict__ b3,
    float* __restrict__ out)
{
    __shared__ __align__(16) float sW1[64];
    __shared__ float sb1[32];
    __shared__ __align__(16) float sW2[1024];
    __shared__ float sb2[32];
    __shared__ float sW3[32];
    __shared__ float sb3w[2];
    __shared__ float sts[NSTEPS + 1];

    const int tid = threadIdx.x;
    for (int i = tid; i < 1024; i += 256) sW2[i] = W2[i];
    if (tid < 64) sW1[tid] = W1[tid];
    if (tid < 32) { sb1[tid] = b1[tid]; sb2[tid] = b2[tid]; sW3[tid] = W3[tid]; }
    if (tid == 0) { sb3w[0] = b3[0]; sb3w[1] = w[0]; }
    for (int i = tid; i < NSTEPS + 1; i += 256) sts[i] = ts[i];
    __syncthreads();

    const int gid = blockIdx.x * 256 + tid;
    const float* np_ = noise + gid;

    float s   = 1.0f;
    float pnl = 0.0f;
    const float b3v = sb3w[0];
    const float wv_ = sb3w[1];

    #pragma unroll 1
    for (int st = 0; st < NSTEPS; ++st) {
        int zr = 0;
        asm volatile("" : "+v"(zr));   // block LICM of weight loads
        const float2* W1r = (const float2*)sW1 + zr;
        const float*  B1  = sb1 + zr;
        const float4* W2r = (const float4*)sW2 + zr;
        const float*  B2  = sb2 + zr;
        const float*  W3r = sW3 + zr;

        const float t  = sts[st];
        const float dt = sts[st + 1] - t;
        const float dW = np_[(size_t)st * BATCH] * __builtin_sqrtf(dt);
        const float sd = s;

        float h, hacc;
        MLP_BODY(W1r, B1, W2r, B2, W3r, b3v, t, s, sd, h, hacc)
        const float hd = h * (1.0f - h) * hacc;

        const float mil = 0.5f * (dW * dW - dt);
        const float g1  = s * h;
        const float dg1 = fmaf(sd, h, s * hd);
        const float snew = s + s * dt + s * dW + sd * mil;
        pnl = pnl + g1 * dt + g1 * dW + dg1 * mil;
        s = snew;
    }

    const float z = fmaxf(0.0f, s - 3.0f);
    const float d = z - pnl - wv_;
    out[gid] = d * d;
}

extern "C" void kernel_launch(void* const* d_in, const int* in_sizes, int n_in,
                              void* d_out, int out_size, void* d_ws, size_t ws_size,
                              hipStream_t stream) {
    const float* noise = (const float*)d_in[0];
    const float* ts    = (const float*)d_in[1];
    const float* w     = (const float*)d_in[2];
    const float* W1    = (const float*)d_in[3];
    const float* b1    = (const float*)d_in[4];
    const float* W2    = (const float*)d_in[5];
    const float* b2    = (const float*)d_in[6];
    const float* W3    = (const float*)d_in[7];
    const float* b3    = (const float*)d_in[8];
    float* out = (float*)d_out;

    const size_t nA   = (size_t)NSTEPS * NPTS;            // entries
    const size_t need = nA * (sizeof(unsigned int) + sizeof(uint2));  // 3 MB

    if (ws_size >= need) {
        unsigned int* A = (unsigned int*)d_ws;
        uint2* T2 = (uint2*)((char*)d_ws + nA * sizeof(unsigned int));

        dim3 tb(256), tg(nA / 256);
        table_eval_kernel<<<tg, tb, 0, stream>>>(ts, W1, b1, W2, b2, W3, b3, A);
        pack_kernel<<<tg, tb, 0, stream>>>(A, T2);
        dim3 pb(256), pg(BATCH / 256);
        path_kernel<<<pg, pb, 0, stream>>>(noise, ts, w, T2, out);
    } else {
        dim3 grid(BATCH / 256), block(256);
        deep_hedging_direct<<<grid, block, 0, stream>>>(noise, ts, w, W1, b1,
                                                        W2, b2, W3, b3, out);
    }
}

// Round 15
// 69.272 us; speedup vs baseline: 1.5128x; 1.0979x over previous
//
#include <hip/hip_runtime.h>
#include <hip/hip_fp16.h>
#include <math.h>

#define BATCH 131072
#define NSTEPS 256
#define LGN 8
#define NPTS 256           // (1 << LGN)
#define ZSPAN 16.0f        // z in [-8, 8]
#define ZSCALE 16.0f       // NPTS / ZSPAN (entries per sigma)
#define DZ 0.0625f         // ZSPAN / NPTS
#define MU_C 0.72134752044448170367f   // (mu - sigma^2/2)/ln2 = 0.5/ln2
#define SD_C 1.4426950408889634f       // sigma/ln2

using f32x2 = __attribute__((ext_vector_type(2))) float;

__device__ __forceinline__ float fast_exp(float x) {
    return __builtin_amdgcn_exp2f(x * 1.44269504088896340736f);
}
__device__ __forceinline__ float fast_rcp(float x) {
    return __builtin_amdgcn_rcpf(x);
}
__device__ __forceinline__ float sigmoidf_fast(float x) {
    return fast_rcp(1.0f + fast_exp(-x));
}

#define REP32(M) M(0) M(1) M(2) M(3) M(4) M(5) M(6) M(7) \
                 M(8) M(9) M(10) M(11) M(12) M(13) M(14) M(15) \
                 M(16) M(17) M(18) M(19) M(20) M(21) M(22) M(23) \
                 M(24) M(25) M(26) M(27) M(28) M(29) M(30) M(31)

#define REP16(M) M(0) M(1) M(2) M(3) M(4) M(5) M(6) M(7) \
                 M(8) M(9) M(10) M(11) M(12) M(13) M(14) M(15)

#define REP16P(M, P) M(0,P) M(1,P) M(2,P) M(3,P) M(4,P) M(5,P) M(6,P) M(7,P) \
                     M(8,P) M(9,P) M(10,P) M(11,P) M(12,P) M(13,P) M(14,P) M(15,P)

// Shared MLP+tangent body (see R4). Produces h and pre-sigmoid tangent acc.
#define MLP_BODY(W1r, B1, W2r, B2, W3r, b3v, t, s, sd, H, HACC) \
    { \
        const float __t = (t), __s = (s), __sd = (sd); \
        f32x2 acc2 = {(b3v), 0.0f}; \
        REP32(MLP_L1) \
        REP32(MLP_ROW) \
        H = sigmoidf_fast(acc2.x); \
        HACC = acc2.y; \
    }

#define MLP_L1(j) f32x2 at##j; { \
    const float2 wv = W1r[j]; \
    const float z  = fmaf(wv.x, __t, fmaf(wv.y, __s, B1[j])); \
    const float zd = wv.y * __sd; \
    const float sg = sigmoidf_fast(z); \
    const float da = sg * (1.0f + z * (1.0f - sg)); \
    at##j = (f32x2){z * sg, da * zd}; }

#define MLP_ROW(j) { \
    const float4 q0 = W2r[(j) * 8 + 0]; \
    const float4 q1 = W2r[(j) * 8 + 1]; \
    const float4 q2 = W2r[(j) * 8 + 2]; \
    const float4 q3 = W2r[(j) * 8 + 3]; \
    const float4 q4 = W2r[(j) * 8 + 4]; \
    const float4 q5 = W2r[(j) * 8 + 5]; \
    const float4 q6 = W2r[(j) * 8 + 6]; \
    const float4 q7 = W2r[(j) * 8 + 7]; \
    f32x2 zza = {B2[j], 0.0f}; \
    f32x2 zzb = {0.0f, 0.0f}; \
    zza += (f32x2){q0.x, q0.x} * at0;  zzb += (f32x2){q0.y, q0.y} * at1; \
    zza += (f32x2){q0.z, q0.z} * at2;  zzb += (f32x2){q0.w, q0.w} * at3; \
    zza += (f32x2){q1.x, q1.x} * at4;  zzb += (f32x2){q1.y, q1.y} * at5; \
    zza += (f32x2){q1.z, q1.z} * at6;  zzb += (f32x2){q1.w, q1.w} * at7; \
    zza += (f32x2){q2.x, q2.x} * at8;  zzb += (f32x2){q2.y, q2.y} * at9; \
    zza += (f32x2){q2.z, q2.z} * at10; zzb += (f32x2){q2.w, q2.w} * at11; \
    zza += (f32x2){q3.x, q3.x} * at12; zzb += (f32x2){q3.y, q3.y} * at13; \
    zza += (f32x2){q3.z, q3.z} * at14; zzb += (f32x2){q3.w, q3.w} * at15; \
    zza += (f32x2){q4.x, q4.x} * at16; zzb += (f32x2){q4.y, q4.y} * at17; \
    zza += (f32x2){q4.z, q4.z} * at18; zzb += (f32x2){q4.w, q4.w} * at19; \
    zza += (f32x2){q5.x, q5.x} * at20; zzb += (f32x2){q5.y, q5.y} * at21; \
    zza += (f32x2){q5.z, q5.z} * at22; zzb += (f32x2){q5.w, q5.w} * at23; \
    zza += (f32x2){q6.x, q6.x} * at24; zzb += (f32x2){q6.y, q6.y} * at25; \
    zza += (f32x2){q6.z, q6.z} * at26; zzb += (f32x2){q6.w, q6.w} * at27; \
    zza += (f32x2){q7.x, q7.x} * at28; zzb += (f32x2){q7.y, q7.y} * at29; \
    zza += (f32x2){q7.z, q7.z} * at30; zzb += (f32x2){q7.w, q7.w} * at31; \
    const f32x2 zzt = zza + zzb; \
    const float zv  = zzt.x; \
    const float sg  = sigmoidf_fast(zv); \
    const float da  = sg * (1.0f + zv * (1.0f - sg)); \
    const float w3  = W3r[j]; \
    acc2 += (f32x2){w3, w3} * (f32x2){zv * sg, da * zzt.y}; \
}

// ---------------------------------------------------------------------------
// Kernel 1a: evaluate packed half2{h, q} at standardized grid points.
// Row st: s = 2^(mu + (k*DZ - 8)*sd), mu = MU_C*t, sd = SD_C*sqrt(t)+eps.
// q = s*dh/ds doubles as the Hermite tangent for cubic interpolation.
// ---------------------------------------------------------------------------
__global__ __launch_bounds__(256) void table_eval_kernel(
    const float* __restrict__ ts,
    const float* __restrict__ W1, const float* __restrict__ b1,
    const float* __restrict__ W2, const float* __restrict__ b2,
    const float* __restrict__ W3, const float* __restrict__ b3,
    unsigned int* __restrict__ A)
{
    __shared__ __align__(16) float sW1[64];
    __shared__ float sb1[32];
    __shared__ __align__(16) float sW2[1024];
    __shared__ float sb2[32];
    __shared__ float sW3[32];
    __shared__ float sb3[1];

    const int tid = threadIdx.x;
    for (int i = tid; i < 1024; i += 256) sW2[i] = W2[i];
    if (tid < 64) sW1[tid] = W1[tid];
    if (tid < 32) { sb1[tid] = b1[tid]; sb2[tid] = b2[tid]; sW3[tid] = W3[tid]; }
    if (tid == 0) sb3[0] = b3[0];
    __syncthreads();

    const float2* W1r = (const float2*)sW1;
    const float*  B1  = sb1;
    const float4* W2r = (const float4*)sW2;
    const float*  B2  = sb2;
    const float*  W3r = sW3;
    const float   b3v = sb3[0];

    const int gid = blockIdx.x * 256 + tid;
    const int st = gid >> LGN;
    const int k  = gid & (NPTS - 1);

    const float t  = ts[st];
    const float mu = MU_C * t;
    const float sd = SD_C * __builtin_sqrtf(t) + 1e-4f;
    const float zz = fmaf((float)k, DZ, -8.0f);
    const float s  = __builtin_amdgcn_exp2f(fmaf(zz, sd, mu));

    float h, hacc;
    MLP_BODY(W1r, B1, W2r, B2, W3r, b3v, t, s, 1.0f, h, hacc)

    const float q = h * (1.0f - h) * hacc * s;   // s * dh/ds
    __half2 p = __floats2half2_rn(h, q);
    A[gid] = *(unsigned int*)&p;
}

// ---------------------------------------------------------------------------
// Kernel 1b: pure-memory pair pack: T2[st][k] = {A[st][k], A[st][k+1]}.
// ---------------------------------------------------------------------------
__global__ __launch_bounds__(256) void pack_kernel(
    const unsigned int* __restrict__ A, uint2* __restrict__ T2)
{
    const int gid = blockIdx.x * 256 + threadIdx.x;
    const int k = gid & (NPTS - 1);
    const unsigned int a = A[gid];
    const unsigned int b = A[gid + (k < NPTS - 1 ? 1 : 0)];
    T2[gid] = make_uint2(a, b);
}

// ---------------------------------------------------------------------------
// Kernel 2: SDE path integration.  R14 structure (16-step chunks, 2-body
// unroll, depth-2 noise prefetch, asm pins) + CUBIC HERMITE interp on the
// 4x-coarser grid: q IS the Hermite tangent, so cubic accuracy comes free
// and the wave gather footprint drops 48 -> 12 cache lines (the R14 bound
// was L2 gather line traffic, not scheduling).
// ---------------------------------------------------------------------------
__global__ __launch_bounds__(256, 1) void path_kernel(
    const float* __restrict__ noise,   // (NSTEPS, BATCH)
    const float* __restrict__ ts,      // (NSTEPS+1)
    const float* __restrict__ wq,      // scalar
    const uint2* __restrict__ T2,      // (NSTEPS, NPTS) paired entries
    float* __restrict__ out)           // (BATCH)
{
    __shared__ float4 sdt4[NSTEPS];    // {dt, sqrt(dt), c', w'}: u = x*w' + c'
    __shared__ float2 scr[NSTEPS];     // {cr, 1/cr}, cr = ln2 / w' (Hermite scale)
    const int tid = threadIdx.x;
    if (tid < NSTEPS) {
        const float t0  = ts[tid];
        const float dtv = ts[tid + 1] - t0;
        const float sdv = SD_C * __builtin_sqrtf(t0) + 1e-4f;
        const float wp  = fast_rcp(sdv) * ZSCALE;
        const float cp  = 8.0f * ZSCALE - MU_C * t0 * wp;
        sdt4[tid] = make_float4(dtv, __builtin_sqrtf(dtv), cp, wp);
        scr[tid]  = make_float2(0.69314718056f * fast_rcp(wp),
                                1.44269504089f * wp);
    }
    __syncthreads();

    const int gid = blockIdx.x * 256 + tid;
    const float* np_ = noise + gid;
    const float umax = (float)NPTS - 1.001f;

    float s   = 1.0f;
    float pnl = 0.0f;

    // preload noise for chunks 0 (set A) and 1 (set B)
    #define NLA(k) float nA##k = np_[(size_t)(k) * BATCH];
    #define NLB(k) float nB##k = np_[(size_t)(16 + k) * BATCH];
    REP16(NLA)
    REP16(NLB)
    #undef NLA
    #undef NLB

    // per-step: s-chain + gather issue
    #define CHK(k, NP) \
        const float4 dq##k = sdt4[base + k]; \
        const float2 cw##k = scr[base + k]; \
        const float dW##k  = NP##k * dq##k.y; \
        const float mil##k = 0.5f * fmaf(dW##k, dW##k, -dq##k.x); \
        const float Af##k  = dq##k.x + dW##k + mil##k; \
        const float sv##k  = s; \
        s = fmaf(s, Af##k, s); \
        const float x##k = __builtin_amdgcn_logf(sv##k); \
        const float u##k = fminf(fmaxf(fmaf(x##k, dq##k.w, dq##k.z), 0.0f), umax); \
        const int   i0##k = (int)u##k; \
        const float f##k  = u##k - (float)i0##k; \
        unsigned long long E##k = \
            ((const unsigned long long*)(T2 + ((size_t)(base + k) << LGN)))[i0##k];

    // noise prefetch for chunk c+2 (overwrites this body's set, already read)
    #define NPF(k, NP) NP##k = np_[(size_t)(pfb + k) * BATCH];

    // consume: cubic Hermite interp (h and its derivative) into pnl
    #define PNK(k) { \
        const uint2 eu = __builtin_bit_cast(uint2, E##k); \
        const float2 a0 = __half22float2(*(const __half2*)&eu.x); \
        const float2 a1 = __half22float2(*(const __half2*)&eu.y); \
        const float uu = f##k; \
        const float m  = uu * uu; \
        const float n  = m * uu; \
        const float dh = a1.x - a0.x; \
        const float ba = fmaf(-2.0f, n, 3.0f * m);            /* 3u^2-2u^3 */ \
        const float bb = fmaf(-2.0f, m, uu) + n;              /* u^3-2u^2+u */ \
        const float bc = n - m;                               /* u^3-u^2 */ \
        const float hh = fmaf(dh, ba, a0.x) \
                       + cw##k.x * fmaf(a0.y, bb, a1.y * bc); \
        const float de = 6.0f * (uu - m);                     /* 6u-6u^2 */ \
        const float df = fmaf(3.0f, m, fmaf(-4.0f, uu, 1.0f));/* 3u^2-4u+1 */ \
        const float dg = fmaf(3.0f, m, -2.0f * uu);           /* 3u^2-2u */ \
        const float qq = fmaf(dh * cw##k.y, de, fmaf(a0.y, df, a1.y * dg)); \
        const float v  = fmaf(qq, mil##k, hh * Af##k); \
        pnl = fmaf(sv##k, v, pnl); }

    #define BODY(cexpr, NP) { \
        const int base = (cexpr) * 16; \
        const int pfb  = min(base + 32, NSTEPS - 16); \
        REP16P(CHK, NP) \
        __builtin_amdgcn_sched_barrier(0); \
        REP16P(NPF, NP) \
        asm volatile("" : "+v"(E0), "+v"(E1), "+v"(E2), "+v"(E3), \
                          "+v"(E4), "+v"(E5), "+v"(E6), "+v"(E7)); \
        asm volatile("" : "+v"(E8),  "+v"(E9),  "+v"(E10), "+v"(E11), \
                          "+v"(E12), "+v"(E13), "+v"(E14), "+v"(E15)); \
        __builtin_amdgcn_sched_barrier(0); \
        REP16(PNK) \
    }

    #pragma unroll 1
    for (int cc = 0; cc < NSTEPS / 32; ++cc) {
        BODY(cc * 2,     nA)
        BODY(cc * 2 + 1, nB)
    }

    #undef BODY
    #undef PNK
    #undef NPF
    #undef CHK

    const float z = fmaxf(0.0f, s - 3.0f);
    const float d = z - pnl - wq[0];
    out[gid] = d * d;
}

// ---------------------------------------------------------------------------
// Fallback: direct per-thread MLP evaluation (R4 kernel) if ws too small.
// ---------------------------------------------------------------------------
__global__ __launch_bounds__(256, 3) void deep_hedging_direct(
    const float* __restrict__ noise, const float* __restrict__ ts,
    const float* __restrict__ w,
    const float* __restrict__ W1, const float* __restrict__ b1,
    const float* __restrict__ W2, const float* __restrict__ b2,
    const float* __restrict__ W3, const float* __restrict__ b3,
    float* __restrict__ out)
{
    __shared__ __align__(16) float sW1[64];
    __shared__ float sb1[32];
    __shared__ __align__(16) float sW2[1024];
    __shared__ float sb2[32];
    __shared__ float sW3[32];
    __shared__ float sb3w[2];
    __shared__ float sts[NSTEPS + 1];

    const int tid = threadIdx.x;
    for (int i = tid; i < 1024; i += 256) sW2[i] = W2[i];
    if (tid < 64) sW1[tid] = W1[tid];
    if (tid < 32) { sb1[tid] = b1[tid]; sb2[tid] = b2[tid]; sW3[tid] = W3[tid]; }
    if (tid == 0) { sb3w[0] = b3[0]; sb3w[1] = w[0]; }
    for (int i = tid; i < NSTEPS + 1; i += 256) sts[i] = ts[i];
    __syncthreads();

    const int gid = blockIdx.x * 256 + tid;
    const float* np_ = noise + gid;

    float s   = 1.0f;
    float pnl = 0.0f;
    const float b3v = sb3w[0];
    const float wv_ = sb3w[1];

    #pragma unroll 1
    for (int st = 0; st < NSTEPS; ++st) {
        int zr = 0;
        asm volatile("" : "+v"(zr));   // block LICM of weight loads
        const float2* W1r = (const float2*)sW1 + zr;
        const float*  B1  = sb1 + zr;
        const float4* W2r = (const float4*)sW2 + zr;
        const float*  B2  = sb2 + zr;
        const float*  W3r = sW3 + zr;

        const float t  = sts[st];
        const float dt = sts[st + 1] - t;
        const float dW = np_[(size_t)st * BATCH] * __builtin_sqrtf(dt);
        const float sd = s;

        float h, hacc;
        MLP_BODY(W1r, B1, W2r, B2, W3r, b3v, t, s, sd, h, hacc)
        const float hd = h * (1.0f - h) * hacc;

        const float mil = 0.5f * (dW * dW - dt);
        const float g1  = s * h;
        const float dg1 = fmaf(sd, h, s * hd);
        const float snew = s + s * dt + s * dW + sd * mil;
        pnl = pnl + g1 * dt + g1 * dW + dg1 * mil;
        s = snew;
    }

    const float z = fmaxf(0.0f, s - 3.0f);
    const float d = z - pnl - wv_;
    out[gid] = d * d;
}

extern "C" void kernel_launch(void* const* d_in, const int* in_sizes, int n_in,
                              void* d_out, int out_size, void* d_ws, size_t ws_size,
                              hipStream_t stream) {
    const float* noise = (const float*)d_in[0];
    const float* ts    = (const float*)d_in[1];
    const float* w     = (const float*)d_in[2];
    const float* W1    = (const float*)d_in[3];
    const float* b1    = (const float*)d_in[4];
    const float* W2    = (const float*)d_in[5];
    const float* b2    = (const float*)d_in[6];
    const float* W3    = (const float*)d_in[7];
    const float* b3    = (const float*)d_in[8];
    float* out = (float*)d_out;

    const size_t nA   = (size_t)NSTEPS * NPTS;            // entries
    const size_t need = nA * (sizeof(unsigned int) + sizeof(uint2));  // 768 KB

    if (ws_size >= need) {
        unsigned int* A = (unsigned int*)d_ws;
        uint2* T2 = (uint2*)((char*)d_ws + nA * sizeof(unsigned int));

        dim3 tb(256), tg(nA / 256);
        table_eval_kernel<<<tg, tb, 0, stream>>>(ts, W1, b1, W2, b2, W3, b3, A);
        pack_kernel<<<tg, tb, 0, stream>>>(A, T2);
        dim3 pb(256), pg(BATCH / 256);
        path_kernel<<<pg, pb, 0, stream>>>(noise, ts, w, T2, out);
    } else {
        dim3 grid(BATCH / 256), block(256);
        deep_hedging_direct<<<grid, block, 0, stream>>>(noise, ts, w, W1, b1,
                                                        W2, b2, W3, b3, out);
    }
}

// Round 16
// 61.929 us; speedup vs baseline: 1.6922x; 1.1186x over previous
//
#include <hip/hip_runtime.h>
#include <hip/hip_fp16.h>
#include <math.h>

#define BATCH 131072
#define NSTEPS 256
#define LGN 7
#define NPTS 128           // (1 << LGN)
#define ZSPAN 12.0f        // z in [-6, 6]
#define ZLO 6.0f
#define ZSCALE (NPTS / ZSPAN)      // entries per sigma (10.667)
#define DZ (ZSPAN / NPTS)          // 0.09375
#define MU_C 0.72134752044448170367f   // (mu - sigma^2/2)/ln2 = 0.5/ln2
#define SD_C 1.4426950408889634f       // sigma/ln2

using f32x2 = __attribute__((ext_vector_type(2))) float;

__device__ __forceinline__ float fast_exp(float x) {
    return __builtin_amdgcn_exp2f(x * 1.44269504088896340736f);
}
__device__ __forceinline__ float fast_rcp(float x) {
    return __builtin_amdgcn_rcpf(x);
}
__device__ __forceinline__ float sigmoidf_fast(float x) {
    return fast_rcp(1.0f + fast_exp(-x));
}

#define REP32(M) M(0) M(1) M(2) M(3) M(4) M(5) M(6) M(7) \
                 M(8) M(9) M(10) M(11) M(12) M(13) M(14) M(15) \
                 M(16) M(17) M(18) M(19) M(20) M(21) M(22) M(23) \
                 M(24) M(25) M(26) M(27) M(28) M(29) M(30) M(31)

#define REP16(M) M(0) M(1) M(2) M(3) M(4) M(5) M(6) M(7) \
                 M(8) M(9) M(10) M(11) M(12) M(13) M(14) M(15)

#define REP16P(M, P) M(0,P) M(1,P) M(2,P) M(3,P) M(4,P) M(5,P) M(6,P) M(7,P) \
                     M(8,P) M(9,P) M(10,P) M(11,P) M(12,P) M(13,P) M(14,P) M(15,P)

// Shared MLP+tangent body (see R4). Produces h and pre-sigmoid tangent acc.
#define MLP_BODY(W1r, B1, W2r, B2, W3r, b3v, t, s, sd, H, HACC) \
    { \
        const float __t = (t), __s = (s), __sd = (sd); \
        f32x2 acc2 = {(b3v), 0.0f}; \
        REP32(MLP_L1) \
        REP32(MLP_ROW) \
        H = sigmoidf_fast(acc2.x); \
        HACC = acc2.y; \
    }

#define MLP_L1(j) f32x2 at##j; { \
    const float2 wv = W1r[j]; \
    const float z  = fmaf(wv.x, __t, fmaf(wv.y, __s, B1[j])); \
    const float zd = wv.y * __sd; \
    const float sg = sigmoidf_fast(z); \
    const float da = sg * (1.0f + z * (1.0f - sg)); \
    at##j = (f32x2){z * sg, da * zd}; }

#define MLP_ROW(j) { \
    const float4 q0 = W2r[(j) * 8 + 0]; \
    const float4 q1 = W2r[(j) * 8 + 1]; \
    const float4 q2 = W2r[(j) * 8 + 2]; \
    const float4 q3 = W2r[(j) * 8 + 3]; \
    const float4 q4 = W2r[(j) * 8 + 4]; \
    const float4 q5 = W2r[(j) * 8 + 5]; \
    const float4 q6 = W2r[(j) * 8 + 6]; \
    const float4 q7 = W2r[(j) * 8 + 7]; \
    f32x2 zza = {B2[j], 0.0f}; \
    f32x2 zzb = {0.0f, 0.0f}; \
    zza += (f32x2){q0.x, q0.x} * at0;  zzb += (f32x2){q0.y, q0.y} * at1; \
    zza += (f32x2){q0.z, q0.z} * at2;  zzb += (f32x2){q0.w, q0.w} * at3; \
    zza += (f32x2){q1.x, q1.x} * at4;  zzb += (f32x2){q1.y, q1.y} * at5; \
    zza += (f32x2){q1.z, q1.z} * at6;  zzb += (f32x2){q1.w, q1.w} * at7; \
    zza += (f32x2){q2.x, q2.x} * at8;  zzb += (f32x2){q2.y, q2.y} * at9; \
    zza += (f32x2){q2.z, q2.z} * at10; zzb += (f32x2){q2.w, q2.w} * at11; \
    zza += (f32x2){q3.x, q3.x} * at12; zzb += (f32x2){q3.y, q3.y} * at13; \
    zza += (f32x2){q3.z, q3.z} * at14; zzb += (f32x2){q3.w, q3.w} * at15; \
    zza += (f32x2){q4.x, q4.x} * at16; zzb += (f32x2){q4.y, q4.y} * at17; \
    zza += (f32x2){q4.z, q4.z} * at18; zzb += (f32x2){q4.w, q4.w} * at19; \
    zza += (f32x2){q5.x, q5.x} * at20; zzb += (f32x2){q5.y, q5.y} * at21; \
    zza += (f32x2){q5.z, q5.z} * at22; zzb += (f32x2){q5.w, q5.w} * at23; \
    zza += (f32x2){q6.x, q6.x} * at24; zzb += (f32x2){q6.y, q6.y} * at25; \
    zza += (f32x2){q6.z, q6.z} * at26; zzb += (f32x2){q6.w, q6.w} * at27; \
    zza += (f32x2){q7.x, q7.x} * at28; zzb += (f32x2){q7.y, q7.y} * at29; \
    zza += (f32x2){q7.z, q7.z} * at30; zzb += (f32x2){q7.w, q7.w} * at31; \
    const f32x2 zzt = zza + zzb; \
    const float zv  = zzt.x; \
    const float sg  = sigmoidf_fast(zv); \
    const float da  = sg * (1.0f + zv * (1.0f - sg)); \
    const float w3  = W3r[j]; \
    acc2 += (f32x2){w3, w3} * (f32x2){zv * sg, da * zzt.y}; \
}

// ---------------------------------------------------------------------------
// Kernel 1a: evaluate packed half2{h, q} at standardized grid points.
// Row st: s = 2^(mu + (k*DZ - ZLO)*sd), mu = MU_C*t, sd = SD_C*sqrt(t)+eps.
// q = s*dh/ds doubles as the Hermite tangent for the h-cubic.
// ---------------------------------------------------------------------------
__global__ __launch_bounds__(256) void table_eval_kernel(
    const float* __restrict__ ts,
    const float* __restrict__ W1, const float* __restrict__ b1,
    const float* __restrict__ W2, const float* __restrict__ b2,
    const float* __restrict__ W3, const float* __restrict__ b3,
    unsigned int* __restrict__ A)
{
    __shared__ __align__(16) float sW1[64];
    __shared__ float sb1[32];
    __shared__ __align__(16) float sW2[1024];
    __shared__ float sb2[32];
    __shared__ float sW3[32];
    __shared__ float sb3[1];

    const int tid = threadIdx.x;
    for (int i = tid; i < 1024; i += 256) sW2[i] = W2[i];
    if (tid < 64) sW1[tid] = W1[tid];
    if (tid < 32) { sb1[tid] = b1[tid]; sb2[tid] = b2[tid]; sW3[tid] = W3[tid]; }
    if (tid == 0) sb3[0] = b3[0];
    __syncthreads();

    const float2* W1r = (const float2*)sW1;
    const float*  B1  = sb1;
    const float4* W2r = (const float4*)sW2;
    const float*  B2  = sb2;
    const float*  W3r = sW3;
    const float   b3v = sb3[0];

    const int gid = blockIdx.x * 256 + tid;
    const int st = gid >> LGN;
    const int k  = gid & (NPTS - 1);

    const float t  = ts[st];
    const float mu = MU_C * t;
    const float sd = SD_C * __builtin_sqrtf(t) + 1e-4f;
    const float zz = fmaf((float)k, DZ, -ZLO);
    const float s  = __builtin_amdgcn_exp2f(fmaf(zz, sd, mu));

    float h, hacc;
    MLP_BODY(W1r, B1, W2r, B2, W3r, b3v, t, s, 1.0f, h, hacc)

    const float q = h * (1.0f - h) * hacc * s;   // s * dh/ds
    __half2 p = __floats2half2_rn(h, q);
    A[gid] = *(unsigned int*)&p;
}

// ---------------------------------------------------------------------------
// Kernel 1b: pure-memory pair pack: T2[st][k] = {A[st][k], A[st][k+1]}.
// ---------------------------------------------------------------------------
__global__ __launch_bounds__(256) void pack_kernel(
    const unsigned int* __restrict__ A, uint2* __restrict__ T2)
{
    const int gid = blockIdx.x * 256 + threadIdx.x;
    const int k = gid & (NPTS - 1);
    const unsigned int a = A[gid];
    const unsigned int b = A[gid + (k < NPTS - 1 ? 1 : 0)];
    T2[gid] = make_uint2(a, b);
}

// ---------------------------------------------------------------------------
// Kernel 2: SDE path integration.  R15 structure (16-step chunks, 2-body
// unroll, depth-2 noise prefetch, asm pins), with:
//  - 128-pt [-6,6]sigma grid (wave gather footprint ~8 cache lines)
//  - cubic Hermite for h (multiplies Af ~ 0.07: accuracy matters)
//  - LINEAR interp for q (multiplies mil ~ 0.004: second-order term)
// ---------------------------------------------------------------------------
__global__ __launch_bounds__(256, 1) void path_kernel(
    const float* __restrict__ noise,   // (NSTEPS, BATCH)
    const float* __restrict__ ts,      // (NSTEPS+1)
    const float* __restrict__ wq,      // scalar
    const uint2* __restrict__ T2,      // (NSTEPS, NPTS) paired entries
    float* __restrict__ out)           // (BATCH)
{
    __shared__ float4 sdt4[NSTEPS];    // {dt, sqrt(dt), c', w'}: u = x*w' + c'
    __shared__ float  scr[NSTEPS];     // cr = ln2 / w' (Hermite tangent scale)
    const int tid = threadIdx.x;
    if (tid < NSTEPS) {
        const float t0  = ts[tid];
        const float dtv = ts[tid + 1] - t0;
        const float sdv = SD_C * __builtin_sqrtf(t0) + 1e-4f;
        const float wp  = fast_rcp(sdv) * ZSCALE;
        const float cp  = ZLO * ZSCALE - MU_C * t0 * wp;
        sdt4[tid] = make_float4(dtv, __builtin_sqrtf(dtv), cp, wp);
        scr[tid]  = 0.69314718056f * fast_rcp(wp);
    }
    __syncthreads();

    const int gid = blockIdx.x * 256 + tid;
    const float* np_ = noise + gid;
    const float umax = (float)NPTS - 1.001f;

    float s   = 1.0f;
    float pnl = 0.0f;

    // preload noise for chunks 0 (set A) and 1 (set B)
    #define NLA(k) float nA##k = np_[(size_t)(k) * BATCH];
    #define NLB(k) float nB##k = np_[(size_t)(16 + k) * BATCH];
    REP16(NLA)
    REP16(NLB)
    #undef NLA
    #undef NLB

    // per-step: s-chain + gather issue
    #define CHK(k, NP) \
        const float4 dq##k = sdt4[base + k]; \
        const float  cr##k = scr[base + k]; \
        const float dW##k  = NP##k * dq##k.y; \
        const float mil##k = 0.5f * fmaf(dW##k, dW##k, -dq##k.x); \
        const float Af##k  = dq##k.x + dW##k + mil##k; \
        const float sv##k  = s; \
        s = fmaf(s, Af##k, s); \
        const float x##k = __builtin_amdgcn_logf(sv##k); \
        const float u##k = fminf(fmaxf(fmaf(x##k, dq##k.w, dq##k.z), 0.0f), umax); \
        const int   i0##k = (int)u##k; \
        const float f##k  = u##k - (float)i0##k; \
        unsigned long long E##k = \
            ((const unsigned long long*)(T2 + ((size_t)(base + k) << LGN)))[i0##k];

    // noise prefetch for chunk c+2 (overwrites this body's set, already read)
    #define NPF(k, NP) NP##k = np_[(size_t)(pfb + k) * BATCH];

    // consume: cubic Hermite for h, linear for q
    #define PNK(k) { \
        const uint2 eu = __builtin_bit_cast(uint2, E##k); \
        const float2 a0 = __half22float2(*(const __half2*)&eu.x); \
        const float2 a1 = __half22float2(*(const __half2*)&eu.y); \
        const float uu = f##k; \
        const float m  = uu * uu; \
        const float n  = m * uu; \
        const float dh = a1.x - a0.x; \
        const float ba = fmaf(-2.0f, n, 3.0f * m);            /* 3u^2-2u^3 */ \
        const float bb = fmaf(-2.0f, m, uu) + n;              /* u^3-2u^2+u */ \
        const float bc = n - m;                               /* u^3-u^2 */ \
        const float hh = fmaf(dh, ba, a0.x) \
                       + cr##k * fmaf(a0.y, bb, a1.y * bc); \
        const float qq = fmaf(uu, a1.y - a0.y, a0.y); \
        const float v  = fmaf(qq, mil##k, hh * Af##k); \
        pnl = fmaf(sv##k, v, pnl); }

    #define BODY(cexpr, NP) { \
        const int base = (cexpr) * 16; \
        const int pfb  = min(base + 32, NSTEPS - 16); \
        REP16P(CHK, NP) \
        __builtin_amdgcn_sched_barrier(0); \
        REP16P(NPF, NP) \
        asm volatile("" : "+v"(E0), "+v"(E1), "+v"(E2), "+v"(E3), \
                          "+v"(E4), "+v"(E5), "+v"(E6), "+v"(E7)); \
        asm volatile("" : "+v"(E8),  "+v"(E9),  "+v"(E10), "+v"(E11), \
                          "+v"(E12), "+v"(E13), "+v"(E14), "+v"(E15)); \
        __builtin_amdgcn_sched_barrier(0); \
        REP16(PNK) \
    }

    #pragma unroll 1
    for (int cc = 0; cc < NSTEPS / 32; ++cc) {
        BODY(cc * 2,     nA)
        BODY(cc * 2 + 1, nB)
    }

    #undef BODY
    #undef PNK
    #undef NPF
    #undef CHK

    const float z = fmaxf(0.0f, s - 3.0f);
    const float d = z - pnl - wq[0];
    out[gid] = d * d;
}

// ---------------------------------------------------------------------------
// Fallback: direct per-thread MLP evaluation (R4 kernel) if ws too small.
// ---------------------------------------------------------------------------
__global__ __launch_bounds__(256, 3) void deep_hedging_direct(
    const float* __restrict__ noise, const float* __restrict__ ts,
    const float* __restrict__ w,
    const float* __restrict__ W1, const float* __restrict__ b1,
    const float* __restrict__ W2, const float* __restrict__ b2,
    const float* __restrict__ W3, const float* __restrict__ b3,
    float* __restrict__ out)
{
    __shared__ __align__(16) float sW1[64];
    __shared__ float sb1[32];
    __shared__ __align__(16) float sW2[1024];
    __shared__ float sb2[32];
    __shared__ float sW3[32];
    __shared__ float sb3w[2];
    __shared__ float sts[NSTEPS + 1];

    const int tid = threadIdx.x;
    for (int i = tid; i < 1024; i += 256) sW2[i] = W2[i];
    if (tid < 64) sW1[tid] = W1[tid];
    if (tid < 32) { sb1[tid] = b1[tid]; sb2[tid] = b2[tid]; sW3[tid] = W3[tid]; }
    if (tid == 0) { sb3w[0] = b3[0]; sb3w[1] = w[0]; }
    for (int i = tid; i < NSTEPS + 1; i += 256) sts[i] = ts[i];
    __syncthreads();

    const int gid = blockIdx.x * 256 + tid;
    const float* np_ = noise + gid;

    float s   = 1.0f;
    float pnl = 0.0f;
    const float b3v = sb3w[0];
    const float wv_ = sb3w[1];

    #pragma unroll 1
    for (int st = 0; st < NSTEPS; ++st) {
        int zr = 0;
        asm volatile("" : "+v"(zr));   // block LICM of weight loads
        const float2* W1r = (const float2*)sW1 + zr;
        const float*  B1  = sb1 + zr;
        const float4* W2r = (const float4*)sW2 + zr;
        const float*  B2  = sb2 + zr;
        const float*  W3r = sW3 + zr;

        const float t  = sts[st];
        const float dt = sts[st + 1] - t;
        const float dW = np_[(size_t)st * BATCH] * __builtin_sqrtf(dt);
        const float sd = s;

        float h, hacc;
        MLP_BODY(W1r, B1, W2r, B2, W3r, b3v, t, s, sd, h, hacc)
        const float hd = h * (1.0f - h) * hacc;

        const float mil = 0.5f * (dW * dW - dt);
        const float g1  = s * h;
        const float dg1 = fmaf(sd, h, s * hd);
        const float snew = s + s * dt + s * dW + sd * mil;
        pnl = pnl + g1 * dt + g1 * dW + dg1 * mil;
        s = snew;
    }

    const float z = fmaxf(0.0f, s - 3.0f);
    const float d = z - pnl - wv_;
    out[gid] = d * d;
}

extern "C" void kernel_launch(void* const* d_in, const int* in_sizes, int n_in,
                              void* d_out, int out_size, void* d_ws, size_t ws_size,
                              hipStream_t stream) {
    const float* noise = (const float*)d_in[0];
    const float* ts    = (const float*)d_in[1];
    const float* w     = (const float*)d_in[2];
    const float* W1    = (const float*)d_in[3];
    const float* b1    = (const float*)d_in[4];
    const float* W2    = (const float*)d_in[5];
    const float* b2    = (const float*)d_in[6];
    const float* W3    = (const float*)d_in[7];
    const float* b3    = (const float*)d_in[8];
    float* out = (float*)d_out;

    const size_t nA   = (size_t)NSTEPS * NPTS;            // entries
    const size_t need = nA * (sizeof(unsigned int) + sizeof(uint2));  // 384 KB

    if (ws_size >= need) {
        unsigned int* A = (unsigned int*)d_ws;
        uint2* T2 = (uint2*)((char*)d_ws + nA * sizeof(unsigned int));

        dim3 tb(256), tg(nA / 256);
        table_eval_kernel<<<tg, tb, 0, stream>>>(ts, W1, b1, W2, b2, W3, b3, A);
        pack_kernel<<<tg, tb, 0, stream>>>(A, T2);
        dim3 pb(256), pg(BATCH / 256);
        path_kernel<<<pg, pb, 0, stream>>>(noise, ts, w, T2, out);
    } else {
        dim3 grid(BATCH / 256), block(256);
        deep_hedging_direct<<<grid, block, 0, stream>>>(noise, ts, w, W1, b1,
                                                        W2, b2, W3, b3, out);
    }
}

// Round 17
// 61.767 us; speedup vs baseline: 1.6967x; 1.0026x over previous
//
#include <hip/hip_runtime.h>
#include <hip/hip_fp16.h>
#include <math.h>

#define BATCH 131072
#define NSTEPS 256
#define LGN 7
#define NPTS 128           // (1 << LGN)
#define ZSPAN 12.0f        // z in [-6, 6]
#define ZLO 6.0f
#define ZSCALE (NPTS / ZSPAN)      // entries per sigma (10.667)
#define DZ (ZSPAN / NPTS)          // 0.09375
#define MU_C 0.72134752044448170367f   // (mu - sigma^2/2)/ln2 = 0.5/ln2
#define SD_C 1.4426950408889634f       // sigma/ln2

using f32x2 = __attribute__((ext_vector_type(2))) float;

__device__ __forceinline__ float fast_exp(float x) {
    return __builtin_amdgcn_exp2f(x * 1.44269504088896340736f);
}
__device__ __forceinline__ float fast_rcp(float x) {
    return __builtin_amdgcn_rcpf(x);
}
__device__ __forceinline__ float sigmoidf_fast(float x) {
    return fast_rcp(1.0f + fast_exp(-x));
}

#define REP32(M) M(0) M(1) M(2) M(3) M(4) M(5) M(6) M(7) \
                 M(8) M(9) M(10) M(11) M(12) M(13) M(14) M(15) \
                 M(16) M(17) M(18) M(19) M(20) M(21) M(22) M(23) \
                 M(24) M(25) M(26) M(27) M(28) M(29) M(30) M(31)

#define REP16(M) M(0) M(1) M(2) M(3) M(4) M(5) M(6) M(7) \
                 M(8) M(9) M(10) M(11) M(12) M(13) M(14) M(15)

// Shared MLP+tangent body (see R4). Produces h and pre-sigmoid tangent acc.
#define MLP_BODY(W1r, B1, W2r, B2, W3r, b3v, t, s, sd, H, HACC) \
    { \
        const float __t = (t), __s = (s), __sd = (sd); \
        f32x2 acc2 = {(b3v), 0.0f}; \
        REP32(MLP_L1) \
        REP32(MLP_ROW) \
        H = sigmoidf_fast(acc2.x); \
        HACC = acc2.y; \
    }

#define MLP_L1(j) f32x2 at##j; { \
    const float2 wv = W1r[j]; \
    const float z  = fmaf(wv.x, __t, fmaf(wv.y, __s, B1[j])); \
    const float zd = wv.y * __sd; \
    const float sg = sigmoidf_fast(z); \
    const float da = sg * (1.0f + z * (1.0f - sg)); \
    at##j = (f32x2){z * sg, da * zd}; }

#define MLP_ROW(j) { \
    const float4 q0 = W2r[(j) * 8 + 0]; \
    const float4 q1 = W2r[(j) * 8 + 1]; \
    const float4 q2 = W2r[(j) * 8 + 2]; \
    const float4 q3 = W2r[(j) * 8 + 3]; \
    const float4 q4 = W2r[(j) * 8 + 4]; \
    const float4 q5 = W2r[(j) * 8 + 5]; \
    const float4 q6 = W2r[(j) * 8 + 6]; \
    const float4 q7 = W2r[(j) * 8 + 7]; \
    f32x2 zza = {B2[j], 0.0f}; \
    f32x2 zzb = {0.0f, 0.0f}; \
    zza += (f32x2){q0.x, q0.x} * at0;  zzb += (f32x2){q0.y, q0.y} * at1; \
    zza += (f32x2){q0.z, q0.z} * at2;  zzb += (f32x2){q0.w, q0.w} * at3; \
    zza += (f32x2){q1.x, q1.x} * at4;  zzb += (f32x2){q1.y, q1.y} * at5; \
    zza += (f32x2){q1.z, q1.z} * at6;  zzb += (f32x2){q1.w, q1.w} * at7; \
    zza += (f32x2){q2.x, q2.x} * at8;  zzb += (f32x2){q2.y, q2.y} * at9; \
    zza += (f32x2){q2.z, q2.z} * at10; zzb += (f32x2){q2.w, q2.w} * at11; \
    zza += (f32x2){q3.x, q3.x} * at12; zzb += (f32x2){q3.y, q3.y} * at13; \
    zza += (f32x2){q3.z, q3.z} * at14; zzb += (f32x2){q3.w, q3.w} * at15; \
    zza += (f32x2){q4.x, q4.x} * at16; zzb += (f32x2){q4.y, q4.y} * at17; \
    zza += (f32x2){q4.z, q4.z} * at18; zzb += (f32x2){q4.w, q4.w} * at19; \
    zza += (f32x2){q5.x, q5.x} * at20; zzb += (f32x2){q5.y, q5.y} * at21; \
    zza += (f32x2){q5.z, q5.z} * at22; zzb += (f32x2){q5.w, q5.w} * at23; \
    zza += (f32x2){q6.x, q6.x} * at24; zzb += (f32x2){q6.y, q6.y} * at25; \
    zza += (f32x2){q6.z, q6.z} * at26; zzb += (f32x2){q6.w, q6.w} * at27; \
    zza += (f32x2){q7.x, q7.x} * at28; zzb += (f32x2){q7.y, q7.y} * at29; \
    zza += (f32x2){q7.z, q7.z} * at30; zzb += (f32x2){q7.w, q7.w} * at31; \
    const f32x2 zzt = zza + zzb; \
    const float zv  = zzt.x; \
    const float sg  = sigmoidf_fast(zv); \
    const float da  = sg * (1.0f + zv * (1.0f - sg)); \
    const float w3  = W3r[j]; \
    acc2 += (f32x2){w3, w3} * (f32x2){zv * sg, da * zzt.y}; \
}

// ---------------------------------------------------------------------------
// Kernel 1: evaluate packed half2{h, q} at standardized grid points and write
// DIRECTLY into the paired table (each value lands in T2[st][k].x and
// T2[st][k-1].y) -- the separate pack kernel is gone.
// ---------------------------------------------------------------------------
__global__ __launch_bounds__(256) void table_eval_kernel(
    const float* __restrict__ ts,
    const float* __restrict__ W1, const float* __restrict__ b1,
    const float* __restrict__ W2, const float* __restrict__ b2,
    const float* __restrict__ W3, const float* __restrict__ b3,
    unsigned int* __restrict__ W)      // = (unsigned int*)T2, 2 words/entry
{
    __shared__ __align__(16) float sW1[64];
    __shared__ float sb1[32];
    __shared__ __align__(16) float sW2[1024];
    __shared__ float sb2[32];
    __shared__ float sW3[32];
    __shared__ float sb3[1];

    const int tid = threadIdx.x;
    for (int i = tid; i < 1024; i += 256) sW2[i] = W2[i];
    if (tid < 64) sW1[tid] = W1[tid];
    if (tid < 32) { sb1[tid] = b1[tid]; sb2[tid] = b2[tid]; sW3[tid] = W3[tid]; }
    if (tid == 0) sb3[0] = b3[0];
    __syncthreads();

    const float2* W1r = (const float2*)sW1;
    const float*  B1  = sb1;
    const float4* W2r = (const float4*)sW2;
    const float*  B2  = sb2;
    const float*  W3r = sW3;
    const float   b3v = sb3[0];

    const int gid = blockIdx.x * 256 + tid;
    const int st = gid >> LGN;
    const int k  = gid & (NPTS - 1);

    const float t  = ts[st];
    const float mu = MU_C * t;
    const float sd = SD_C * __builtin_sqrtf(t) + 1e-4f;
    const float zz = fmaf((float)k, DZ, -ZLO);
    const float s  = __builtin_amdgcn_exp2f(fmaf(zz, sd, mu));

    float h, hacc;
    MLP_BODY(W1r, B1, W2r, B2, W3r, b3v, t, s, 1.0f, h, hacc)

    const float q = h * (1.0f - h) * hacc * s;   // s * dh/ds (Hermite tangent)
    __half2 p = __floats2half2_rn(h, q);
    const unsigned int pv = *(unsigned int*)&p;

    W[2 * gid] = pv;                       // T2[st][k].x
    if (k > 0)         W[2 * gid - 1] = pv;  // T2[st][k-1].y
    if (k == NPTS - 1) W[2 * gid + 1] = pv;  // row-end clamp
}

// ---------------------------------------------------------------------------
// Kernel 2: SDE path integration.  32 steps per iteration (two 16-step CH
// blocks back-to-back -- the s-chain never depends on PN -- then 32 noise
// prefetches, one pin, two PN blocks).  32 gathers + 32 noise loads in
// flight; live state across the pin is 5 regs/step (E,f,P=sv*Af,Q=sv*mil).
// ---------------------------------------------------------------------------
__global__ __launch_bounds__(256, 1) void path_kernel(
    const float* __restrict__ noise,   // (NSTEPS, BATCH)
    const float* __restrict__ ts,      // (NSTEPS+1)
    const float* __restrict__ wq,      // scalar
    const uint2* __restrict__ T2,      // (NSTEPS, NPTS) paired entries
    float* __restrict__ out)           // (BATCH)
{
    __shared__ float4 sdt4[NSTEPS];    // {dt, sqrt(dt), c', w'}: u = x*w' + c'
    __shared__ float  scr[NSTEPS];     // cr = ln2 / w' (Hermite tangent scale)
    const int tid = threadIdx.x;
    if (tid < NSTEPS) {
        const float t0  = ts[tid];
        const float dtv = ts[tid + 1] - t0;
        const float sdv = SD_C * __builtin_sqrtf(t0) + 1e-4f;
        const float wp  = fast_rcp(sdv) * ZSCALE;
        const float cp  = ZLO * ZSCALE - MU_C * t0 * wp;
        sdt4[tid] = make_float4(dtv, __builtin_sqrtf(dtv), cp, wp);
        scr[tid]  = 0.69314718056f * fast_rcp(wp);
    }
    __syncthreads();

    const int gid = blockIdx.x * 256 + tid;
    const float* np_ = noise + gid;
    const float umax = (float)NPTS - 1.001f;

    float s   = 1.0f;
    float pnl = 0.0f;

    // preload noise for steps 0-15 (set A) and 16-31 (set B)
    #define NL0(k) float nA##k = np_[(size_t)(k) * BATCH]; \
                   float nB##k = np_[(size_t)(16 + k) * BATCH];
    REP16(NL0)
    #undef NL0

    // per-step: s-chain + gather issue + P/Q precompute
    #define CHK(k, G, NPv, BASE) \
        const float4 dq##G##k = sdt4[(BASE) + k]; \
        const float dW##G##k  = NPv##k * dq##G##k.y; \
        const float mil##G##k = 0.5f * fmaf(dW##G##k, dW##G##k, -dq##G##k.x); \
        const float Af##G##k  = dq##G##k.x + dW##G##k + mil##G##k; \
        const float sv##G##k  = s; \
        s = fmaf(s, Af##G##k, s); \
        const float P##G##k = sv##G##k * Af##G##k; \
        const float Q##G##k = sv##G##k * mil##G##k; \
        const float x##G##k = __builtin_amdgcn_logf(sv##G##k); \
        const float u##G##k = \
            fminf(fmaxf(fmaf(x##G##k, dq##G##k.w, dq##G##k.z), 0.0f), umax); \
        const int   i0##G##k = (int)u##G##k; \
        const float f##G##k  = u##G##k - (float)i0##G##k; \
        unsigned long long E##G##k = \
            ((const unsigned long long*)(T2 + ((size_t)((BASE) + k) << LGN)))[i0##G##k];

    // noise prefetch (rows PFB..PFB+15 into set NPv; consumed next iteration)
    #define NPF(k, NPv, PFB) NPv##k = np_[(size_t)((PFB) + k) * BATCH];

    // consume: cubic Hermite for h, linear for q; pnl += hh*P + qq*Q
    #define PNK(k, G, BASE) { \
        const uint2 eu = __builtin_bit_cast(uint2, E##G##k); \
        const float2 a0 = __half22float2(*(const __half2*)&eu.x); \
        const float2 a1 = __half22float2(*(const __half2*)&eu.y); \
        const float cr = scr[(BASE) + k]; \
        const float uu = f##G##k; \
        const float m  = uu * uu; \
        const float n  = m * uu; \
        const float dh = a1.x - a0.x; \
        const float ba = fmaf(-2.0f, n, 3.0f * m);            /* 3u^2-2u^3 */ \
        const float bb = fmaf(-2.0f, m, uu) + n;              /* u^3-2u^2+u */ \
        const float bc = n - m;                               /* u^3-u^2 */ \
        const float hh = fmaf(dh, ba, a0.x) + cr * fmaf(a0.y, bb, a1.y * bc); \
        const float qq = fmaf(uu, a1.y - a0.y, a0.y); \
        pnl = fmaf(hh, P##G##k, fmaf(qq, Q##G##k, pnl)); }

    #define CHA(k) CHK(k, A, nA, baseA)
    #define CHB(k) CHK(k, B, nB, baseB)
    #define NPA(k) NPF(k, nA, pfA)
    #define NPB(k) NPF(k, nB, pfB)
    #define PNA(k) PNK(k, A, baseA)
    #define PNB(k) PNK(k, B, baseB)

    #pragma unroll 1
    for (int cc = 0; cc < NSTEPS / 32; ++cc) {
        const int baseA = cc * 32;
        const int baseB = cc * 32 + 16;
        const int pfA = min(baseA + 32, NSTEPS - 16);
        const int pfB = min(baseB + 32, NSTEPS - 16);

        REP16(CHA)
        REP16(CHB)
        __builtin_amdgcn_sched_barrier(0);
        REP16(NPA)
        REP16(NPB)
        asm volatile("" : "+v"(EA0), "+v"(EA1), "+v"(EA2),  "+v"(EA3),
                          "+v"(EA4), "+v"(EA5), "+v"(EA6),  "+v"(EA7));
        asm volatile("" : "+v"(EA8), "+v"(EA9), "+v"(EA10), "+v"(EA11),
                          "+v"(EA12),"+v"(EA13),"+v"(EA14), "+v"(EA15));
        asm volatile("" : "+v"(EB0), "+v"(EB1), "+v"(EB2),  "+v"(EB3),
                          "+v"(EB4), "+v"(EB5), "+v"(EB6),  "+v"(EB7));
        asm volatile("" : "+v"(EB8), "+v"(EB9), "+v"(EB10), "+v"(EB11),
                          "+v"(EB12),"+v"(EB13),"+v"(EB14), "+v"(EB15));
        __builtin_amdgcn_sched_barrier(0);
        REP16(PNA)
        REP16(PNB)
    }

    #undef CHA
    #undef CHB
    #undef NPA
    #undef NPB
    #undef PNA
    #undef PNB
    #undef PNK
    #undef NPF
    #undef CHK

    const float z = fmaxf(0.0f, s - 3.0f);
    const float d = z - pnl - wq[0];
    out[gid] = d * d;
}

// ---------------------------------------------------------------------------
// Fallback: direct per-thread MLP evaluation (R4 kernel) if ws too small.
// ---------------------------------------------------------------------------
__global__ __launch_bounds__(256, 3) void deep_hedging_direct(
    const float* __restrict__ noise, const float* __restrict__ ts,
    const float* __restrict__ w,
    const float* __restrict__ W1, const float* __restrict__ b1,
    const float* __restrict__ W2, const float* __restrict__ b2,
    const float* __restrict__ W3, const float* __restrict__ b3,
    float* __restrict__ out)
{
    __shared__ __align__(16) float sW1[64];
    __shared__ float sb1[32];
    __shared__ __align__(16) float sW2[1024];
    __shared__ float sb2[32];
    __shared__ float sW3[32];
    __shared__ float sb3w[2];
    __shared__ float sts[NSTEPS + 1];

    const int tid = threadIdx.x;
    for (int i = tid; i < 1024; i += 256) sW2[i] = W2[i];
    if (tid < 64) sW1[tid] = W1[tid];
    if (tid < 32) { sb1[tid] = b1[tid]; sb2[tid] = b2[tid]; sW3[tid] = W3[tid]; }
    if (tid == 0) { sb3w[0] = b3[0]; sb3w[1] = w[0]; }
    for (int i = tid; i < NSTEPS + 1; i += 256) sts[i] = ts[i];
    __syncthreads();

    const int gid = blockIdx.x * 256 + tid;
    const float* np_ = noise + gid;

    float s   = 1.0f;
    float pnl = 0.0f;
    const float b3v = sb3w[0];
    const float wv_ = sb3w[1];

    #pragma unroll 1
    for (int st = 0; st < NSTEPS; ++st) {
        int zr = 0;
        asm volatile("" : "+v"(zr));   // block LICM of weight loads
        const float2* W1r = (const float2*)sW1 + zr;
        const float*  B1  = sb1 + zr;
        const float4* W2r = (const float4*)sW2 + zr;
        const float*  B2  = sb2 + zr;
        const float*  W3r = sW3 + zr;

        const float t  = sts[st];
        const float dt = sts[st + 1] - t;
        const float dW = np_[(size_t)st * BATCH] * __builtin_sqrtf(dt);
        const float sd = s;

        float h, hacc;
        MLP_BODY(W1r, B1, W2r, B2, W3r, b3v, t, s, sd, h, hacc)
        const float hd = h * (1.0f - h) * hacc;

        const float mil = 0.5f * (dW * dW - dt);
        const float g1  = s * h;
        const float dg1 = fmaf(sd, h, s * hd);
        const float snew = s + s * dt + s * dW + sd * mil;
        pnl = pnl + g1 * dt + g1 * dW + dg1 * mil;
        s = snew;
    }

    const float z = fmaxf(0.0f, s - 3.0f);
    const float d = z - pnl - wv_;
    out[gid] = d * d;
}

extern "C" void kernel_launch(void* const* d_in, const int* in_sizes, int n_in,
                              void* d_out, int out_size, void* d_ws, size_t ws_size,
                              hipStream_t stream) {
    const float* noise = (const float*)d_in[0];
    const float* ts    = (const float*)d_in[1];
    const float* w     = (const float*)d_in[2];
    const float* W1    = (const float*)d_in[3];
    const float* b1    = (const float*)d_in[4];
    const float* W2    = (const float*)d_in[5];
    const float* b2    = (const float*)d_in[6];
    const float* W3    = (const float*)d_in[7];
    const float* b3    = (const float*)d_in[8];
    float* out = (float*)d_out;

    const size_t nA   = (size_t)NSTEPS * NPTS;           // entries
    const size_t need = nA * sizeof(uint2);              // 256 KB

    if (ws_size >= need) {
        uint2* T2 = (uint2*)d_ws;

        dim3 tb(256), tg(nA / 256);
        table_eval_kernel<<<tg, tb, 0, stream>>>(ts, W1, b1, W2, b2, W3, b3,
                                                 (unsigned int*)T2);
        dim3 pb(256), pg(BATCH / 256);
        path_kernel<<<pg, pb, 0, stream>>>(noise, ts, w, T2, out);
    } else {
        dim3 grid(BATCH / 256), block(256);
        deep_hedging_direct<<<grid, block, 0, stream>>>(noise, ts, w, W1, b1,
                                                        W2, b2, W3, b3, out);
    }
}